// Round 9
// baseline (14418.738 us; speedup 1.0000x reference)
//
#include <hip/hip_runtime.h>
#include <math.h>

#define BB 4096
#define TT 48
#define DD 32
#define HH 256
#define LL 128
#define HID 256
#define EE 8
#define NHZ 48
#define NS 8              // RK4 macro steps (dense-output Hermite between knots)
#define NTEMB (2*NS+1)    // 17 precomputed time-embeddings (knots + midpoints)

__device__ __forceinline__ float sigm_f(float x) {
    return 1.0f / (1.0f + __expf(-x));
}
__device__ __forceinline__ float tanh_f(float x) {
    x = fminf(fmaxf(x, -15.0f), 15.0f);
    float e = __expf(2.0f * x);
    return (e - 1.0f) / (e + 1.0f);
}
__device__ __forceinline__ float4 axpy4(float s, float4 a, float4 z) {
    return make_float4(fmaf(s, a.x, z.x), fmaf(s, a.y, z.y),
                       fmaf(s, a.z, z.z), fmaf(s, a.w, z.w));
}

// ---------------- prep kernels ----------------
// pack4: src [OUT][IN] row-major -> dst[(k>>2)*OUT + o] float4 = w[o][4k..4k+3]

__global__ void pack4_k(const float* __restrict__ src, float* __restrict__ dst, int OUT, int IN) {
    int i = blockIdx.x * 256 + threadIdx.x;
    if (i < OUT * IN) {
        int o = i / IN, k = i % IN;
        dst[((k >> 2) * OUT + o) * 4 + (k & 3)] = src[i];
    }
}

__global__ void temb_k(const float* __restrict__ tproj_w, const float* __restrict__ tproj_b,
                       float* __restrict__ tembs) {
    int i = blockIdx.x * 64 + threadIdx.x;
    if (i >= NTEMB) return;
    float t = (float)i / (float)(2 * NS);
    const float PI = 3.14159265358979323846f;
    float emb[8];
    #pragma unroll
    for (int m = 0; m < 4; ++m) {
        float pos = t * (float)(m + 1) * PI;
        emb[m]     = sinf(pos);
        emb[4 + m] = cosf(pos);
    }
    #pragma unroll
    for (int o = 0; o < 8; ++o) {
        float a = tproj_b[o];
        #pragma unroll
        for (int k = 0; k < 8; ++k) a = fmaf(tproj_w[o * 8 + k], emb[k], a);
        tembs[i * 8 + o] = a;
    }
}

// ---------------- GRU encoder (+ fused z0 projection) ----------------
// Round-8 geometry (proven): 16 rows/block, 512 threads, grid 256.
// NEW: register ping-pong double-buffering of the k4 inner loops so LDS/L2
// load latency overlaps the FMA bursts (round-8 VGPR=60 had no headroom).

__global__ __launch_bounds__(512, 2) void gru_k(
    const float* __restrict__ Xp, const float* __restrict__ Mp,
    const float* __restrict__ w_ihp,   // packed [16][768][4]
    const float* __restrict__ w_hhp,   // packed [64][768][4]
    const float* __restrict__ b_ih, const float* __restrict__ b_hh,
    const float* __restrict__ z0_wp,   // packed [64][256][4]
    const float* __restrict__ z0_b,
    float* __restrict__ out_mean, float* __restrict__ out_lv) {

    __shared__ __align__(16) float h[16 * HH];   // 16KB
    __shared__ __align__(16) float u[16 * 64];   // 4KB
    __shared__ float obs[16];

    int tid = threadIdx.x, blk = blockIdx.x;
    int j = tid & 255, rb = (tid >> 8) * 8;

    const float4* hq  = (const float4*)h;
    const float4* uq  = (const float4*)u;
    const float4* wih = (const float4*)w_ihp;
    const float4* whh = (const float4*)w_hhp;
    const float4* z0q = (const float4*)z0_wp;

    for (int e = tid; e < 16 * HH; e += 512) h[e] = 0.0f;

    float brz0 = b_ih[j]       + b_hh[j];
    float brz1 = b_ih[256 + j] + b_hh[256 + j];
    float bin_ = b_ih[512 + j];
    float bhn_ = b_hh[512 + j];
    __syncthreads();

    for (int t = TT - 1; t >= 0; --t) {
        if (tid < 256) {
            int r = tid >> 4, c4 = tid & 15;
            const float* base = (c4 < 8 ? Xp : Mp) + (size_t)(blk * 16 + r) * (TT * DD) + t * DD;
            ((float4*)u)[tid] = ((const float4*)base)[c4 & 7];
        }
        __syncthreads();
        if (tid < 16) {
            float sm = 0.0f;
            #pragma unroll
            for (int i = 8; i < 16; ++i) {
                float4 v = uq[tid * 16 + i];
                sm += v.x + v.y + v.z + v.w;
            }
            obs[tid] = (sm > 0.0f) ? 1.0f : 0.0f;
        }

        float ar[8], az[8], an[8], ah[8];
        #pragma unroll
        for (int r = 0; r < 8; ++r) { ar[r] = brz0; az[r] = brz1; an[r] = bin_; ah[r] = bhn_; }

        // ---- input contribution: 16 packed k4, ping-pong 2-deep ----
        {
            float4 vA[8], wrA, wzA, wnA, vB[8], wrB, wzB, wnB;
            #pragma unroll
            for (int r = 0; r < 8; ++r) vA[r] = uq[(rb + r) * 16 + 0];
            wrA = wih[j]; wzA = wih[256 + j]; wnA = wih[512 + j];
            for (int k4 = 0; k4 < 16; k4 += 2) {
                #pragma unroll
                for (int r = 0; r < 8; ++r) vB[r] = uq[(rb + r) * 16 + (k4 + 1)];
                wrB = wih[(k4+1)*768 + j]; wzB = wih[(k4+1)*768 + 256 + j]; wnB = wih[(k4+1)*768 + 512 + j];
                #pragma unroll
                for (int r = 0; r < 8; ++r) {
                    float4 v = vA[r];
                    ar[r] = fmaf(wrA.x, v.x, ar[r]); az[r] = fmaf(wzA.x, v.x, az[r]); an[r] = fmaf(wnA.x, v.x, an[r]);
                    ar[r] = fmaf(wrA.y, v.y, ar[r]); az[r] = fmaf(wzA.y, v.y, az[r]); an[r] = fmaf(wnA.y, v.y, an[r]);
                    ar[r] = fmaf(wrA.z, v.z, ar[r]); az[r] = fmaf(wzA.z, v.z, az[r]); an[r] = fmaf(wnA.z, v.z, an[r]);
                    ar[r] = fmaf(wrA.w, v.w, ar[r]); az[r] = fmaf(wzA.w, v.w, az[r]); an[r] = fmaf(wnA.w, v.w, an[r]);
                }
                if (k4 + 2 < 16) {
                    #pragma unroll
                    for (int r = 0; r < 8; ++r) vA[r] = uq[(rb + r) * 16 + (k4 + 2)];
                    wrA = wih[(k4+2)*768 + j]; wzA = wih[(k4+2)*768 + 256 + j]; wnA = wih[(k4+2)*768 + 512 + j];
                }
                #pragma unroll
                for (int r = 0; r < 8; ++r) {
                    float4 v = vB[r];
                    ar[r] = fmaf(wrB.x, v.x, ar[r]); az[r] = fmaf(wzB.x, v.x, az[r]); an[r] = fmaf(wnB.x, v.x, an[r]);
                    ar[r] = fmaf(wrB.y, v.y, ar[r]); az[r] = fmaf(wzB.y, v.y, az[r]); an[r] = fmaf(wnB.y, v.y, an[r]);
                    ar[r] = fmaf(wrB.z, v.z, ar[r]); az[r] = fmaf(wzB.z, v.z, az[r]); an[r] = fmaf(wnB.z, v.z, an[r]);
                    ar[r] = fmaf(wrB.w, v.w, ar[r]); az[r] = fmaf(wzB.w, v.w, az[r]); an[r] = fmaf(wnB.w, v.w, an[r]);
                }
            }
        }

        // ---- hidden contribution: 64 packed k4, ping-pong 2-deep ----
        {
            float4 vA[8], wrA, wzA, wnA, vB[8], wrB, wzB, wnB;
            #pragma unroll
            for (int r = 0; r < 8; ++r) vA[r] = hq[(rb + r) * 64 + 0];
            wrA = whh[j]; wzA = whh[256 + j]; wnA = whh[512 + j];
            for (int k4 = 0; k4 < 64; k4 += 2) {
                #pragma unroll
                for (int r = 0; r < 8; ++r) vB[r] = hq[(rb + r) * 64 + (k4 + 1)];
                wrB = whh[(k4+1)*768 + j]; wzB = whh[(k4+1)*768 + 256 + j]; wnB = whh[(k4+1)*768 + 512 + j];
                #pragma unroll
                for (int r = 0; r < 8; ++r) {
                    float4 v = vA[r];
                    ar[r] = fmaf(wrA.x, v.x, ar[r]); az[r] = fmaf(wzA.x, v.x, az[r]); ah[r] = fmaf(wnA.x, v.x, ah[r]);
                    ar[r] = fmaf(wrA.y, v.y, ar[r]); az[r] = fmaf(wzA.y, v.y, az[r]); ah[r] = fmaf(wnA.y, v.y, ah[r]);
                    ar[r] = fmaf(wrA.z, v.z, ar[r]); az[r] = fmaf(wzA.z, v.z, az[r]); ah[r] = fmaf(wnA.z, v.z, ah[r]);
                    ar[r] = fmaf(wrA.w, v.w, ar[r]); az[r] = fmaf(wzA.w, v.w, az[r]); ah[r] = fmaf(wnA.w, v.w, ah[r]);
                }
                if (k4 + 2 < 64) {
                    #pragma unroll
                    for (int r = 0; r < 8; ++r) vA[r] = hq[(rb + r) * 64 + (k4 + 2)];
                    wrA = whh[(k4+2)*768 + j]; wzA = whh[(k4+2)*768 + 256 + j]; wnA = whh[(k4+2)*768 + 512 + j];
                }
                #pragma unroll
                for (int r = 0; r < 8; ++r) {
                    float4 v = vB[r];
                    ar[r] = fmaf(wrB.x, v.x, ar[r]); az[r] = fmaf(wzB.x, v.x, az[r]); ah[r] = fmaf(wnB.x, v.x, ah[r]);
                    ar[r] = fmaf(wrB.y, v.y, ar[r]); az[r] = fmaf(wzB.y, v.y, az[r]); ah[r] = fmaf(wnB.y, v.y, ah[r]);
                    ar[r] = fmaf(wrB.z, v.z, ar[r]); az[r] = fmaf(wzB.z, v.z, az[r]); ah[r] = fmaf(wnB.z, v.z, ah[r]);
                    ar[r] = fmaf(wrB.w, v.w, ar[r]); az[r] = fmaf(wzB.w, v.w, az[r]); ah[r] = fmaf(wnB.w, v.w, ah[r]);
                }
            }
        }

        float hnew[8], hold[8];
        #pragma unroll
        for (int r = 0; r < 8; ++r) {
            float rg = sigm_f(ar[r]);
            float zg = sigm_f(az[r]);
            float n  = tanh_f(an[r] + rg * ah[r]);
            float hv = h[(rb + r) * HH + j];
            hold[r] = hv;
            hnew[r] = (1.0f - zg) * n + zg * hv;
        }
        __syncthreads();
        #pragma unroll
        for (int r = 0; r < 8; ++r) {
            float o = obs[rb + r];
            h[(rb + r) * HH + j] = o * hnew[r] + (1.0f - o) * hold[r];
        }
        __syncthreads();
    }

    // fused z0 projection
    float zr_[8];
    #pragma unroll
    for (int r = 0; r < 8; ++r) zr_[r] = z0_b[j];
    for (int k4 = 0; k4 < 64; ++k4) {
        float4 w = z0q[k4 * 256 + j];
        #pragma unroll
        for (int r = 0; r < 8; ++r) {
            float4 v = hq[(rb + r) * 64 + k4];
            zr_[r] = fmaf(w.x, v.x, zr_[r]);
            zr_[r] = fmaf(w.y, v.y, zr_[r]);
            zr_[r] = fmaf(w.z, v.z, zr_[r]);
            zr_[r] = fmaf(w.w, v.w, zr_[r]);
        }
    }
    int row0 = blk * 16 + rb;
    if (j < 128) {
        #pragma unroll
        for (int r = 0; r < 8; ++r) out_mean[(row0 + r) * LL + j] = zr_[r];
    } else {
        #pragma unroll
        for (int r = 0; r < 8; ++r) out_lv[(row0 + r) * LL + (j - 128)] = zr_[r];
    }
}

// ---------------- ODE dynamics eval: 512 threads, 16 rows ----------------
// Separate h1/h2 buffers (3 barriers/eval) + register ping-pong in each phase.

__device__ __forceinline__ void ode_f512(
    const float* __restrict__ in, float* __restrict__ h1, float* __restrict__ h2,
    float* __restrict__ out,
    const float4* __restrict__ w1q, const float4* __restrict__ w2q, const float4* __restrict__ w3q,
    const float* __restrict__ temb,   // 8 floats (global, L2)
    float b1j, float b2j, float b3o, int tid) {

    int j  = tid & 255;  int rb = (tid >> 8) * 8;   // phases A,B: 8 rows
    int od = tid & 127;  int rc = (tid >> 7) * 4;   // phase C: 4 rows

    const float4* inq = (const float4*)in;
    const float4* h1q = (const float4*)h1;
    const float4* h2q = (const float4*)h2;

    // phase A: h1 = tanh([z,temb] @ w1.T + b1)
    float4 wt0 = w1q[32 * 256 + j];
    float4 wt1 = w1q[33 * 256 + j];
    float tacc = b1j;
    tacc = fmaf(wt0.x, temb[0], tacc); tacc = fmaf(wt0.y, temb[1], tacc);
    tacc = fmaf(wt0.z, temb[2], tacc); tacc = fmaf(wt0.w, temb[3], tacc);
    tacc = fmaf(wt1.x, temb[4], tacc); tacc = fmaf(wt1.y, temb[5], tacc);
    tacc = fmaf(wt1.z, temb[6], tacc); tacc = fmaf(wt1.w, temb[7], tacc);
    float a[8];
    #pragma unroll
    for (int r = 0; r < 8; ++r) a[r] = tacc;
    {
        float4 vA[8], wA, vB[8], wB;
        #pragma unroll
        for (int r = 0; r < 8; ++r) vA[r] = inq[(rb + r) * 32 + 0];
        wA = w1q[j];
        for (int k4 = 0; k4 < 32; k4 += 2) {
            #pragma unroll
            for (int r = 0; r < 8; ++r) vB[r] = inq[(rb + r) * 32 + (k4 + 1)];
            wB = w1q[(k4 + 1) * 256 + j];
            #pragma unroll
            for (int r = 0; r < 8; ++r) {
                float4 v = vA[r];
                a[r] = fmaf(wA.x, v.x, a[r]); a[r] = fmaf(wA.y, v.y, a[r]);
                a[r] = fmaf(wA.z, v.z, a[r]); a[r] = fmaf(wA.w, v.w, a[r]);
            }
            if (k4 + 2 < 32) {
                #pragma unroll
                for (int r = 0; r < 8; ++r) vA[r] = inq[(rb + r) * 32 + (k4 + 2)];
                wA = w1q[(k4 + 2) * 256 + j];
            }
            #pragma unroll
            for (int r = 0; r < 8; ++r) {
                float4 v = vB[r];
                a[r] = fmaf(wB.x, v.x, a[r]); a[r] = fmaf(wB.y, v.y, a[r]);
                a[r] = fmaf(wB.z, v.z, a[r]); a[r] = fmaf(wB.w, v.w, a[r]);
            }
        }
    }
    #pragma unroll
    for (int r = 0; r < 8; ++r) h1[(rb + r) * HID + j] = tanh_f(a[r]);
    __syncthreads();

    // phase B: h2 = tanh(h1 @ w2.T + b2)
    float c[8];
    #pragma unroll
    for (int r = 0; r < 8; ++r) c[r] = b2j;
    {
        float4 vA[8], wA, vB[8], wB;
        #pragma unroll
        for (int r = 0; r < 8; ++r) vA[r] = h1q[(rb + r) * 64 + 0];
        wA = w2q[j];
        for (int k4 = 0; k4 < 64; k4 += 2) {
            #pragma unroll
            for (int r = 0; r < 8; ++r) vB[r] = h1q[(rb + r) * 64 + (k4 + 1)];
            wB = w2q[(k4 + 1) * 256 + j];
            #pragma unroll
            for (int r = 0; r < 8; ++r) {
                float4 v = vA[r];
                c[r] = fmaf(wA.x, v.x, c[r]); c[r] = fmaf(wA.y, v.y, c[r]);
                c[r] = fmaf(wA.z, v.z, c[r]); c[r] = fmaf(wA.w, v.w, c[r]);
            }
            if (k4 + 2 < 64) {
                #pragma unroll
                for (int r = 0; r < 8; ++r) vA[r] = h1q[(rb + r) * 64 + (k4 + 2)];
                wA = w2q[(k4 + 2) * 256 + j];
            }
            #pragma unroll
            for (int r = 0; r < 8; ++r) {
                float4 v = vB[r];
                c[r] = fmaf(wB.x, v.x, c[r]); c[r] = fmaf(wB.y, v.y, c[r]);
                c[r] = fmaf(wB.z, v.z, c[r]); c[r] = fmaf(wB.w, v.w, c[r]);
            }
        }
    }
    #pragma unroll
    for (int r = 0; r < 8; ++r) h2[(rb + r) * HID + j] = tanh_f(c[r]);
    __syncthreads();

    // phase C: out = h2 @ w3.T + b3 (4 rows per thread at out-dim od)
    float d[4];
    #pragma unroll
    for (int r = 0; r < 4; ++r) d[r] = b3o;
    {
        float4 vA[4], wA, vB[4], wB;
        #pragma unroll
        for (int r = 0; r < 4; ++r) vA[r] = h2q[(rc + r) * 64 + 0];
        wA = w3q[od];
        for (int k4 = 0; k4 < 64; k4 += 2) {
            #pragma unroll
            for (int r = 0; r < 4; ++r) vB[r] = h2q[(rc + r) * 64 + (k4 + 1)];
            wB = w3q[(k4 + 1) * 128 + od];
            #pragma unroll
            for (int r = 0; r < 4; ++r) {
                float4 v = vA[r];
                d[r] = fmaf(wA.x, v.x, d[r]); d[r] = fmaf(wA.y, v.y, d[r]);
                d[r] = fmaf(wA.z, v.z, d[r]); d[r] = fmaf(wA.w, v.w, d[r]);
            }
            if (k4 + 2 < 64) {
                #pragma unroll
                for (int r = 0; r < 4; ++r) vA[r] = h2q[(rc + r) * 64 + (k4 + 2)];
                wA = w3q[(k4 + 2) * 128 + od];
            }
            #pragma unroll
            for (int r = 0; r < 4; ++r) {
                float4 v = vB[r];
                d[r] = fmaf(wB.x, v.x, d[r]); d[r] = fmaf(wB.y, v.y, d[r]);
                d[r] = fmaf(wB.z, v.z, d[r]); d[r] = fmaf(wB.w, v.w, d[r]);
            }
        }
    }
    #pragma unroll
    for (int r = 0; r < 4; ++r) out[(rc + r) * LL + od] = d[r];
    __syncthreads();
}

// ---------------- ODE (8-step RK4 + Hermite dense output) + head ----------------
// Round-8 launch geometry (grid 256, 512 thr, (512,2)); LDS 88KB, 1 block/CU.

__global__ __launch_bounds__(512, 2) void ode_head_k(
    const float* __restrict__ zinit,
    const float* __restrict__ w1p, const float* __restrict__ w2p, const float* __restrict__ w3p,
    const float* __restrict__ b1, const float* __restrict__ b2, const float* __restrict__ b3,
    const float* __restrict__ tembs,
    const float* __restrict__ shw1g, const float* __restrict__ shb1,
    const float* __restrict__ shw2, const float* __restrict__ shb2,
    float* __restrict__ out_haz, float* __restrict__ out_surv, float* __restrict__ out_pg) {

    __shared__ __align__(16) float bufA [16 * LL];   // 8KB  (z at knot s)
    __shared__ __align__(16) float bufB [16 * LL];   // 8KB  (z at knot s+1)
    __shared__ __align__(16) float bufFP[16 * LL];   // 8KB  (f at knot s)
    __shared__ __align__(16) float bufFN[16 * LL];   // 8KB  (f at knot s+1 / scratch)
    __shared__ __align__(16) float ztl  [16 * LL];   // 8KB  (stage state / z-theta)
    __shared__ __align__(16) float hb1  [16 * HID];  // 16KB
    __shared__ __align__(16) float hb2  [16 * HID];  // 16KB
    __shared__ __align__(16) float w1h  [32 * 128];  // 16KB head W1 packed [k4][unit][4]

    int tid = threadIdx.x, blk = blockIdx.x;
    int j = tid & 255, od = tid & 127;
    int s5 = tid & 31, rh = tid >> 5;     // head role: unit s5, row rh

    float b1j = b1[j], b2j = b2[j], b3o = b3[od];
    float w2s = shw2[s5], b1s = shb1[s5], b2s = shb2[0];
    float cum_r = 0.0f;

    const float4* w1q = (const float4*)w1p;
    const float4* w2q = (const float4*)w2p;
    const float4* w3q = (const float4*)w3p;
    const float4* w1hq = (const float4*)w1h;

    float* zA = bufA; float* zB = bufB;
    float* fP = bufFP; float* fN = bufFN;

    ((float4*)zA)[tid] = ((const float4*)(zinit + (size_t)blk * 2048))[tid];
    // pack head W1 [32][128] -> [k4][unit] float4 (conflict-free lane-s5 reads)
    for (int e = tid; e < 32 * 128; e += 512) {
        int u = e >> 7, k = e & 127;
        w1h[((k >> 2) * 32 + u) * 4 + (k & 3)] = shw1g[e];
    }
    __syncthreads();

    // f0 = f(z0, t=0)
    ode_f512(zA, hb1, hb2, fP, w1q, w2q, w3q, tembs, b1j, b2j, b3o, tid);

    const float Hh = 1.0f / (float)NS;

    for (int st = 0; st < NS; ++st) {
        float4 ka, zr0;
        {   // k1 = fP (FSAL)
            float4 f = ((const float4*)fP)[tid];
            zr0 = ((const float4*)zA)[tid];
            ka = f;
            ((float4*)ztl)[tid] = axpy4(0.5f * Hh, f, zr0);
        }
        __syncthreads();
        ode_f512(ztl, hb1, hb2, fN, w1q, w2q, w3q, tembs + (2 * st + 1) * 8, b1j, b2j, b3o, tid); // k2
        {
            float4 f = ((const float4*)fN)[tid];
            ka = axpy4(2.0f, f, ka);
            ((float4*)ztl)[tid] = axpy4(0.5f * Hh, f, zr0);
        }
        __syncthreads();
        ode_f512(ztl, hb1, hb2, fN, w1q, w2q, w3q, tembs + (2 * st + 1) * 8, b1j, b2j, b3o, tid); // k3
        {
            float4 f = ((const float4*)fN)[tid];
            ka = axpy4(2.0f, f, ka);
            ((float4*)ztl)[tid] = axpy4(Hh, f, zr0);
        }
        __syncthreads();
        ode_f512(ztl, hb1, hb2, fN, w1q, w2q, w3q, tembs + (2 * st + 2) * 8, b1j, b2j, b3o, tid); // k4
        {
            float4 f = ((const float4*)fN)[tid];
            float s6 = Hh / 6.0f;
            float4 kk = make_float4(ka.x + f.x, ka.y + f.y, ka.z + f.z, ka.w + f.w);
            ((float4*)zB)[tid] = axpy4(s6, kk, zr0);
        }
        __syncthreads();
        // f_{s+1} (next step's k1, and Hermite right-slope)
        ode_f512(zB, hb1, hb2, fN, w1q, w2q, w3q, tembs + (2 * st + 2) * 8, b1j, b2j, b3o, tid);

        // ---- emit head at output points inside [st/NS, (st+1)/NS] via Hermite ----
        int jlo = (47 * st + NS - 1) / NS;
        int jhi = (st == NS - 1) ? 47 : (47 * (st + 1) + NS - 1) / NS - 1;
        for (int jp = jlo; jp <= jhi; ++jp) {
            float th  = ((float)NS * (float)jp - 47.0f * (float)st) * (1.0f / 47.0f);
            float th2 = th * th, th3 = th2 * th;
            float c0 = 2.0f * th3 - 3.0f * th2 + 1.0f;
            float c1 = 3.0f * th2 - 2.0f * th3;
            float c2 = Hh * (th3 - 2.0f * th2 + th);
            float c3 = Hh * (th3 - th2);
            {
                float4 za = ((const float4*)zA)[tid];
                float4 zb = ((const float4*)zB)[tid];
                float4 fa = ((const float4*)fP)[tid];
                float4 fb = ((const float4*)fN)[tid];
                float4 zv;
                zv.x = c0*za.x + c1*zb.x + c2*fa.x + c3*fb.x;
                zv.y = c0*za.y + c1*zb.y + c2*fa.y + c3*fb.y;
                zv.z = c0*za.z + c1*zb.z + c2*fa.z + c3*fb.z;
                zv.w = c0*za.w + c1*zb.w + c2*fa.w + c3*fb.w;
                ((float4*)ztl)[tid] = zv;
            }
            __syncthreads();
            {
                float aa = b1s;
                const float4* zrow = (const float4*)(ztl + rh * LL);
                for (int k4 = 0; k4 < 32; ++k4) {
                    float4 w = w1hq[k4 * 32 + s5];
                    float4 v = zrow[k4];
                    aa = fmaf(w.x, v.x, aa); aa = fmaf(w.y, v.y, aa);
                    aa = fmaf(w.z, v.z, aa); aa = fmaf(w.w, v.w, aa);
                }
                float p = fmaxf(aa, 0.0f) * w2s;
                p += __shfl_xor(p, 1);  p += __shfl_xor(p, 2);
                p += __shfl_xor(p, 4);  p += __shfl_xor(p, 8);
                p += __shfl_xor(p, 16);
                float hz = sigm_f(p + b2s);
                float sv = __expf(cum_r);
                cum_r += __logf(1.0f - hz + 1e-7f);
                if (s5 == 0) {
                    int row = blk * 16 + rh;
                    out_haz [row * NHZ + jp] = hz;
                    out_surv[row * NHZ + jp] = sv;
                    if (jp == NHZ - 1) out_pg[row] = 1.0f - sv;
                }
            }
            __syncthreads();
        }

        // roll buffers
        float* t0 = zA; zA = zB; zB = t0;
        t0 = fP; fP = fN; fN = t0;
    }
}

// ---------------- launch ----------------

extern "C" void kernel_launch(void* const* d_in, const int* in_sizes, int n_in,
                              void* d_out, int out_size, void* d_ws, size_t ws_size,
                              hipStream_t stream) {
    const float* X        = (const float*)d_in[0];
    const float* Mask     = (const float*)d_in[1];
    const float* gru_w_ih = (const float*)d_in[2];
    const float* gru_w_hh = (const float*)d_in[3];
    const float* gru_b_ih = (const float*)d_in[4];
    const float* gru_b_hh = (const float*)d_in[5];
    const float* z0_w     = (const float*)d_in[6];
    const float* z0_b     = (const float*)d_in[7];
    const float* tproj_w  = (const float*)d_in[8];
    const float* tproj_b  = (const float*)d_in[9];
    const float* ode_w1   = (const float*)d_in[10];
    const float* ode_b1   = (const float*)d_in[11];
    const float* ode_w2   = (const float*)d_in[12];
    const float* ode_b2   = (const float*)d_in[13];
    const float* ode_w3   = (const float*)d_in[14];
    const float* ode_b3   = (const float*)d_in[15];
    const float* sh_w1    = (const float*)d_in[16];
    const float* sh_b1    = (const float*)d_in[17];
    const float* sh_w2    = (const float*)d_in[18];
    const float* sh_b2    = (const float*)d_in[19];

    float* ws    = (float*)d_ws;
    float* w_ihp = ws;                    // 64*768    = 49152
    float* w_hhp = w_ihp + 49152;         // 256*768   = 196608
    float* z0_wp = w_hhp + 196608;        // 256*256   = 65536
    float* w1p   = z0_wp + 65536;         // 136*256   = 34816
    float* w2p   = w1p   + 34816;         // 256*256   = 65536
    float* w3p   = w2p   + 65536;         // 256*128   = 32768
    float* tembs = w3p   + 32768;         // 17*8      = 136

    float* out      = (float*)d_out;
    float* out_haz  = out;                              // 4096*48
    float* out_surv = out + 196608;                     // 4096*48
    float* out_mean = out + 393216;                     // 4096*128
    float* out_lv   = out + 917504;                     // 4096*128
    float* out_pg   = out + 1441792;                    // 4096

    pack4_k<<<(768*64  + 255) / 256, 256, 0, stream>>>(gru_w_ih, w_ihp, 768, 64);
    pack4_k<<<(768*256 + 255) / 256, 256, 0, stream>>>(gru_w_hh, w_hhp, 768, 256);
    pack4_k<<<(256*256 + 255) / 256, 256, 0, stream>>>(z0_w,     z0_wp, 256, 256);
    pack4_k<<<(256*136 + 255) / 256, 256, 0, stream>>>(ode_w1,   w1p,   256, 136);
    pack4_k<<<(256*256 + 255) / 256, 256, 0, stream>>>(ode_w2,   w2p,   256, 256);
    pack4_k<<<(128*256 + 255) / 256, 256, 0, stream>>>(ode_w3,   w3p,   128, 256);
    temb_k<<<1, 64, 0, stream>>>(tproj_w, tproj_b, tembs);

    gru_k<<<BB / 16, 512, 0, stream>>>(X, Mask, w_ihp, w_hhp, gru_b_ih, gru_b_hh,
                                       z0_wp, z0_b, out_mean, out_lv);

    ode_head_k<<<BB / 16, 512, 0, stream>>>(out_mean, w1p, w2p, w3p,
                                            ode_b1, ode_b2, ode_b3, tembs,
                                            sh_w1, sh_b1, sh_w2, sh_b2,
                                            out_haz, out_surv, out_pg);
}

// Round 10
// 1434.573 us; speedup vs baseline: 10.0509x; 10.0509x over previous
//
#include <hip/hip_runtime.h>
#include <math.h>

#define BB 4096
#define TT 48
#define DD 32
#define HH 256
#define LL 128
#define HID 256
#define EE 8
#define NHZ 48
#define NS 8              // RK4 macro steps (dense-output Hermite between knots)
#define NTEMB (2*NS+1)    // 17 precomputed time-embeddings

typedef __attribute__((ext_vector_type(8))) short bf16x8;   // 8 bf16 = 4 VGPRs
typedef __attribute__((ext_vector_type(4))) float f32x4;

#define MFMA_BF16(a,b,c) __builtin_amdgcn_mfma_f32_16x16x32_bf16((a),(b),(c),0,0,0)

__device__ __forceinline__ float sigm_f(float x) {
    return 1.0f / (1.0f + __expf(-x));
}
__device__ __forceinline__ float tanh_f(float x) {
    x = fminf(fmaxf(x, -15.0f), 15.0f);
    float e = __expf(2.0f * x);
    return (e - 1.0f) / (e + 1.0f);
}
__device__ __forceinline__ float4 axpy4(float s, float4 a, float4 z) {
    return make_float4(fmaf(s, a.x, z.x), fmaf(s, a.y, z.y),
                       fmaf(s, a.z, z.z), fmaf(s, a.w, z.w));
}
__device__ __forceinline__ unsigned short f2bf(float x) {   // RNE fp32->bf16
    union { float f; unsigned u; } a; a.f = x;
    unsigned r = a.u + 0x7FFFu + ((a.u >> 16) & 1u);
    return (unsigned short)(r >> 16);
}

// ---------------- prep kernels ----------------
// pack4 (fp32, for ODE): src [OUT][IN] -> dst[(k>>2)*OUT+o] float4 = w[o][4k..4k+3]

__global__ void pack4_k(const float* __restrict__ src, float* __restrict__ dst, int OUT, int IN) {
    int i = blockIdx.x * 256 + threadIdx.x;
    if (i < OUT * IN) {
        int o = i / IN, k = i % IN;
        dst[((k >> 2) * OUT + o) * 4 + (k & 3)] = src[i];
    }
}

__global__ void temb_k(const float* __restrict__ tproj_w, const float* __restrict__ tproj_b,
                       float* __restrict__ tembs) {
    int i = blockIdx.x * 64 + threadIdx.x;
    if (i >= NTEMB) return;
    float t = (float)i / (float)(2 * NS);
    const float PI = 3.14159265358979323846f;
    float emb[8];
    #pragma unroll
    for (int m = 0; m < 4; ++m) {
        float pos = t * (float)(m + 1) * PI;
        emb[m]     = sinf(pos);
        emb[4 + m] = cosf(pos);
    }
    #pragma unroll
    for (int o = 0; o < 8; ++o) {
        float a = tproj_b[o];
        #pragma unroll
        for (int k = 0; k < 8; ++k) a = fmaf(tproj_w[o * 8 + k], emb[k], a);
        tembs[i * 8 + o] = a;
    }
}

// B-fragment packers (bf16). Fragment = 512 bf16: element (lane*8+j) holds
// B[k][n] with k = ks*32 + (lane>>4)*8 + j, n = nt*16 + (lane&15).

__global__ void packBrz_k(const float* __restrict__ w_ih, const float* __restrict__ w_hh,
                          unsigned short* __restrict__ dst) {
    int i = blockIdx.x * 256 + threadIdx.x;      // 32 nt * 10 ks * 512
    if (i >= 32 * 10 * 512) return;
    int frag = i >> 9, e = i & 511;
    int lane = e >> 3, j = e & 7;
    int nt = frag / 10, ks = frag % 10;
    int k = ks * 32 + ((lane >> 4) << 3) + j;
    int n = nt * 16 + (lane & 15);               // gate rows 0..511 (r then z)
    float v = (k < 64) ? w_ih[n * 64 + k] : w_hh[n * 256 + (k - 64)];
    dst[i] = f2bf(v);
}

__global__ void packB_k(const float* __restrict__ src, unsigned short* __restrict__ dst,
                        int K, int NT, int NKS) {
    int i = blockIdx.x * 256 + threadIdx.x;
    if (i >= NT * NKS * 512) return;
    int frag = i >> 9, e = i & 511;
    int lane = e >> 3, j = e & 7;
    int nt = frag / NKS, ks = frag % NKS;
    int k = ks * 32 + ((lane >> 4) << 3) + j;
    int n = nt * 16 + (lane & 15);
    dst[i] = f2bf(src[n * K + k]);
}

// ---------------- GRU encoder via MFMA (+ fused z0 projection) ----------------
// 16 rows/block, 512 threads (8 waves), grid 256. Wave w owns hidden-col
// groups 2w, 2w+1 (16 cols each). Per t: one 16x16x32 MFMA chain per gate.
// h state lives in registers (lane statically owns (m, hcol) per C/D layout).
// h_bf: bf16 LDS, XOR-swizzled (byte ^= (row&7)<<4) for conflict-free A-reads.

__global__ __launch_bounds__(512, 2) void gru_mfma_k(
    const float* __restrict__ Xp, const float* __restrict__ Mp,
    const unsigned short* __restrict__ Brz,   // [32 nt][10 ks][512]
    const unsigned short* __restrict__ Bnu,   // [16 nt][ 2 ks][512]
    const unsigned short* __restrict__ Bnh,   // [16 nt][ 8 ks][512]
    const unsigned short* __restrict__ Bz0,   // [16 nt][ 8 ks][512]
    const float* __restrict__ b_ih, const float* __restrict__ b_hh,
    const float* __restrict__ z0_b,
    float* __restrict__ out_mean, float* __restrict__ out_lv) {

    __shared__ unsigned short h_bf[16 * 256];  // 8KB, swizzled
    __shared__ unsigned short u_bf[16 * 64];   // 2KB, swizzled
    __shared__ float obs[16];

    int tid = threadIdx.x, blk = blockIdx.x;
    int lane = tid & 63, w = tid >> 6;
    int l4 = lane >> 4, l15 = lane & 15;

    for (int e = tid; e < 16 * 256; e += 512) h_bf[e] = 0;

    // per-lane gate biases + hidden col for 2 groups
    float brz0[2], brz1[2], bin_[2], bhn_[2];
    int hcol[2];
    #pragma unroll
    for (int gg = 0; gg < 2; ++gg) {
        int n = (2 * w + gg) * 16 + l15;
        hcol[gg] = n;
        brz0[gg] = b_ih[n]       + b_hh[n];
        brz1[gg] = b_ih[256 + n] + b_hh[256 + n];
        bin_[gg] = b_ih[512 + n];
        bhn_[gg] = b_hh[512 + n];
    }
    float h_st[2][4] = {{0,0,0,0},{0,0,0,0}};   // h_old for (m=l4*4+q, hcol[gg])

    __syncthreads();

    int arow = l15, asw = (arow & 7) << 4;

    for (int t = TT - 1; t >= 0; --t) {
        // ---- phase 0: stage u_bf, obs; read h A-frags (previous h) ----
        if (tid < 256) {
            int r = tid >> 4, c4 = tid & 15;
            const float* base = (c4 < 8 ? Xp : Mp) + (size_t)(blk * 16 + r) * (TT * DD) + t * DD;
            float4 v = ((const float4*)base)[c4 & 7];
            ushort4 p;
            p.x = f2bf(v.x); p.y = f2bf(v.y); p.z = f2bf(v.z); p.w = f2bf(v.w);
            int k0 = (c4 < 8) ? c4 * 4 : 32 + (c4 - 8) * 4;
            int off = r * 128 + ((k0 * 2) ^ ((r & 7) << 4));
            *(ushort4*)((char*)u_bf + off) = p;
        }
        if (tid < 16) {
            const float4* mrow = (const float4*)(Mp + (size_t)(blk * 16 + tid) * (TT * DD) + t * DD);
            float s = 0.0f;
            #pragma unroll
            for (int i = 0; i < 8; ++i) { float4 v = mrow[i]; s += v.x + v.y + v.z + v.w; }
            obs[tid] = (s > 0.0f) ? 1.0f : 0.0f;
        }
        bf16x8 ah[8];
        #pragma unroll
        for (int ks = 0; ks < 8; ++ks)
            ah[ks] = *(const bf16x8*)((const char*)h_bf + (arow * 512 + ((ks * 64 + l4 * 16) ^ asw)));
        __syncthreads();

        // ---- phase 1: u A-frags, MFMA chains, gate fuse, h writes ----
        bf16x8 au[2];
        #pragma unroll
        for (int ks = 0; ks < 2; ++ks)
            au[ks] = *(const bf16x8*)((const char*)u_bf + (arow * 128 + ((ks * 64 + l4 * 16) ^ asw)));

        #pragma unroll
        for (int gg = 0; gg < 2; ++gg) {
            int g = 2 * w + gg;
            f32x4 accr = {0,0,0,0}, accz = {0,0,0,0}, acci = {0,0,0,0}, acch = {0,0,0,0};
            #pragma unroll
            for (int ks = 0; ks < 10; ++ks) {
                bf16x8 a = (ks < 2) ? au[ks] : ah[ks - 2];
                bf16x8 br = *(const bf16x8*)(Brz + ((g * 10 + ks) * 512 + lane * 8));
                bf16x8 bz = *(const bf16x8*)(Brz + (((16 + g) * 10 + ks) * 512 + lane * 8));
                accr = MFMA_BF16(a, br, accr);
                accz = MFMA_BF16(a, bz, accz);
            }
            #pragma unroll
            for (int ks = 0; ks < 2; ++ks) {
                bf16x8 b = *(const bf16x8*)(Bnu + ((g * 2 + ks) * 512 + lane * 8));
                acci = MFMA_BF16(au[ks], b, acci);
            }
            #pragma unroll
            for (int ks = 0; ks < 8; ++ks) {
                bf16x8 b = *(const bf16x8*)(Bnh + ((g * 8 + ks) * 512 + lane * 8));
                acch = MFMA_BF16(ah[ks], b, acch);
            }
            #pragma unroll
            for (int q = 0; q < 4; ++q) {
                int m = l4 * 4 + q;
                float rg = sigm_f(accr[q] + brz0[gg]);
                float zg = sigm_f(accz[q] + brz1[gg]);
                float nn = tanh_f(acci[q] + bin_[gg] + rg * (acch[q] + bhn_[gg]));
                float hnew = (1.0f - zg) * nn + zg * h_st[gg][q];
                float o = obs[m];
                float hs = o * hnew + (1.0f - o) * h_st[gg][q];
                h_st[gg][q] = hs;
                int off = m * 512 + ((hcol[gg] * 2) ^ ((m & 7) << 4));
                *(unsigned short*)((char*)h_bf + off) = f2bf(hs);
            }
        }
        __syncthreads();
    }

    // ---- fused z0 projection: wave w -> tiles 2w, 2w+1 ----
    bf16x8 ahf[8];
    #pragma unroll
    for (int ks = 0; ks < 8; ++ks)
        ahf[ks] = *(const bf16x8*)((const char*)h_bf + (arow * 512 + ((ks * 64 + l4 * 16) ^ asw)));
    #pragma unroll
    for (int gg = 0; gg < 2; ++gg) {
        int nt = 2 * w + gg;
        f32x4 acc = {0,0,0,0};
        #pragma unroll
        for (int ks = 0; ks < 8; ++ks) {
            bf16x8 b = *(const bf16x8*)(Bz0 + ((nt * 8 + ks) * 512 + lane * 8));
            acc = MFMA_BF16(ahf[ks], b, acc);
        }
        int n = nt * 16 + l15;
        float bb = z0_b[n];
        #pragma unroll
        for (int q = 0; q < 4; ++q) {
            int m = l4 * 4 + q;
            int row = blk * 16 + m;
            float v = acc[q] + bb;
            if (n < 128) out_mean[row * LL + n] = v;
            else         out_lv  [row * LL + (n - 128)] = v;
        }
    }
}

// ---------------- ODE dynamics eval: 512 threads, 16 rows (round-8 exact) ----------------

__device__ __forceinline__ void ode_f512(
    const float* __restrict__ in, float* __restrict__ h1, float* __restrict__ h2,
    float* __restrict__ out,
    const float4* __restrict__ w1q, const float4* __restrict__ w2q, const float4* __restrict__ w3q,
    const float* __restrict__ temb,
    float b1j, float b2j, float b3o, int tid) {

    int j  = tid & 255;  int rb = (tid >> 8) * 8;
    int od = tid & 127;  int rc = (tid >> 7) * 4;

    const float4* inq = (const float4*)in;
    const float4* h1q = (const float4*)h1;
    const float4* h2q = (const float4*)h2;

    float4 wt0 = w1q[32 * 256 + j];
    float4 wt1 = w1q[33 * 256 + j];
    float tacc = b1j;
    tacc = fmaf(wt0.x, temb[0], tacc); tacc = fmaf(wt0.y, temb[1], tacc);
    tacc = fmaf(wt0.z, temb[2], tacc); tacc = fmaf(wt0.w, temb[3], tacc);
    tacc = fmaf(wt1.x, temb[4], tacc); tacc = fmaf(wt1.y, temb[5], tacc);
    tacc = fmaf(wt1.z, temb[6], tacc); tacc = fmaf(wt1.w, temb[7], tacc);
    float a[8];
    #pragma unroll
    for (int r = 0; r < 8; ++r) a[r] = tacc;
    for (int k4 = 0; k4 < 32; ++k4) {
        float4 w = w1q[k4 * 256 + j];
        #pragma unroll
        for (int r = 0; r < 8; ++r) {
            float4 v = inq[(rb + r) * 32 + k4];
            a[r] = fmaf(w.x, v.x, a[r]); a[r] = fmaf(w.y, v.y, a[r]);
            a[r] = fmaf(w.z, v.z, a[r]); a[r] = fmaf(w.w, v.w, a[r]);
        }
    }
    #pragma unroll
    for (int r = 0; r < 8; ++r) h1[(rb + r) * HID + j] = tanh_f(a[r]);
    __syncthreads();

    float c[8];
    #pragma unroll
    for (int r = 0; r < 8; ++r) c[r] = b2j;
    for (int k4 = 0; k4 < 64; ++k4) {
        float4 w = w2q[k4 * 256 + j];
        #pragma unroll
        for (int r = 0; r < 8; ++r) {
            float4 v = h1q[(rb + r) * 64 + k4];
            c[r] = fmaf(w.x, v.x, c[r]); c[r] = fmaf(w.y, v.y, c[r]);
            c[r] = fmaf(w.z, v.z, c[r]); c[r] = fmaf(w.w, v.w, c[r]);
        }
    }
    #pragma unroll
    for (int r = 0; r < 8; ++r) h2[(rb + r) * HID + j] = tanh_f(c[r]);
    __syncthreads();

    float d[4];
    #pragma unroll
    for (int r = 0; r < 4; ++r) d[r] = b3o;
    for (int k4 = 0; k4 < 64; ++k4) {
        float4 w = w3q[k4 * 128 + od];
        #pragma unroll
        for (int r = 0; r < 4; ++r) {
            float4 v = h2q[(rc + r) * 64 + k4];
            d[r] = fmaf(w.x, v.x, d[r]); d[r] = fmaf(w.y, v.y, d[r]);
            d[r] = fmaf(w.z, v.z, d[r]); d[r] = fmaf(w.w, v.w, d[r]);
        }
    }
    #pragma unroll
    for (int r = 0; r < 4; ++r) out[(rc + r) * LL + od] = d[r];
    __syncthreads();
}

// ---------------- ODE (8-step RK4 + Hermite dense output) + head (round-8 exact) ----------------

__global__ __launch_bounds__(512, 2) void ode_head_k(
    const float* __restrict__ zinit,
    const float* __restrict__ w1p, const float* __restrict__ w2p, const float* __restrict__ w3p,
    const float* __restrict__ b1, const float* __restrict__ b2, const float* __restrict__ b3,
    const float* __restrict__ tembs,
    const float* __restrict__ shw1g, const float* __restrict__ shb1,
    const float* __restrict__ shw2, const float* __restrict__ shb2,
    float* __restrict__ out_haz, float* __restrict__ out_surv, float* __restrict__ out_pg) {

    __shared__ __align__(16) float bufA [16 * LL];
    __shared__ __align__(16) float bufB [16 * LL];
    __shared__ __align__(16) float bufFP[16 * LL];
    __shared__ __align__(16) float bufFN[16 * LL];
    __shared__ __align__(16) float ztl  [16 * LL];
    __shared__ __align__(16) float hb1  [16 * HID];
    __shared__ __align__(16) float hb2  [16 * HID];
    __shared__ __align__(16) float w1h  [32 * 128];

    int tid = threadIdx.x, blk = blockIdx.x;
    int j = tid & 255, od = tid & 127;
    int s5 = tid & 31, rh = tid >> 5;

    float b1j = b1[j], b2j = b2[j], b3o = b3[od];
    float w2s = shw2[s5], b1s = shb1[s5], b2s = shb2[0];
    float cum_r = 0.0f;

    const float4* w1q = (const float4*)w1p;
    const float4* w2q = (const float4*)w2p;
    const float4* w3q = (const float4*)w3p;
    const float4* w1hq = (const float4*)w1h;

    float* zA = bufA; float* zB = bufB;
    float* fP = bufFP; float* fN = bufFN;

    ((float4*)zA)[tid] = ((const float4*)(zinit + (size_t)blk * 2048))[tid];
    for (int e = tid; e < 32 * 128; e += 512) {
        int u = e >> 7, k = e & 127;
        w1h[((k >> 2) * 32 + u) * 4 + (k & 3)] = shw1g[e];
    }
    __syncthreads();

    ode_f512(zA, hb1, hb2, fP, w1q, w2q, w3q, tembs, b1j, b2j, b3o, tid);

    const float Hh = 1.0f / (float)NS;

    for (int st = 0; st < NS; ++st) {
        float4 ka, zr0;
        {
            float4 f = ((const float4*)fP)[tid];
            zr0 = ((const float4*)zA)[tid];
            ka = f;
            ((float4*)ztl)[tid] = axpy4(0.5f * Hh, f, zr0);
        }
        __syncthreads();
        ode_f512(ztl, hb1, hb2, fN, w1q, w2q, w3q, tembs + (2 * st + 1) * 8, b1j, b2j, b3o, tid);
        {
            float4 f = ((const float4*)fN)[tid];
            ka = axpy4(2.0f, f, ka);
            ((float4*)ztl)[tid] = axpy4(0.5f * Hh, f, zr0);
        }
        __syncthreads();
        ode_f512(ztl, hb1, hb2, fN, w1q, w2q, w3q, tembs + (2 * st + 1) * 8, b1j, b2j, b3o, tid);
        {
            float4 f = ((const float4*)fN)[tid];
            ka = axpy4(2.0f, f, ka);
            ((float4*)ztl)[tid] = axpy4(Hh, f, zr0);
        }
        __syncthreads();
        ode_f512(ztl, hb1, hb2, fN, w1q, w2q, w3q, tembs + (2 * st + 2) * 8, b1j, b2j, b3o, tid);
        {
            float4 f = ((const float4*)fN)[tid];
            float s6 = Hh / 6.0f;
            float4 kk = make_float4(ka.x + f.x, ka.y + f.y, ka.z + f.z, ka.w + f.w);
            ((float4*)zB)[tid] = axpy4(s6, kk, zr0);
        }
        __syncthreads();
        ode_f512(zB, hb1, hb2, fN, w1q, w2q, w3q, tembs + (2 * st + 2) * 8, b1j, b2j, b3o, tid);

        int jlo = (47 * st + NS - 1) / NS;
        int jhi = (st == NS - 1) ? 47 : (47 * (st + 1) + NS - 1) / NS - 1;
        for (int jp = jlo; jp <= jhi; ++jp) {
            float th  = ((float)NS * (float)jp - 47.0f * (float)st) * (1.0f / 47.0f);
            float th2 = th * th, th3 = th2 * th;
            float c0 = 2.0f * th3 - 3.0f * th2 + 1.0f;
            float c1 = 3.0f * th2 - 2.0f * th3;
            float c2 = Hh * (th3 - 2.0f * th2 + th);
            float c3 = Hh * (th3 - th2);
            {
                float4 za = ((const float4*)zA)[tid];
                float4 zb = ((const float4*)zB)[tid];
                float4 fa = ((const float4*)fP)[tid];
                float4 fb = ((const float4*)fN)[tid];
                float4 zv;
                zv.x = c0*za.x + c1*zb.x + c2*fa.x + c3*fb.x;
                zv.y = c0*za.y + c1*zb.y + c2*fa.y + c3*fb.y;
                zv.z = c0*za.z + c1*zb.z + c2*fa.z + c3*fb.z;
                zv.w = c0*za.w + c1*zb.w + c2*fa.w + c3*fb.w;
                ((float4*)ztl)[tid] = zv;
            }
            __syncthreads();
            {
                float aa = b1s;
                const float4* zrow = (const float4*)(ztl + rh * LL);
                for (int k4 = 0; k4 < 32; ++k4) {
                    float4 w = w1hq[k4 * 32 + s5];
                    float4 v = zrow[k4];
                    aa = fmaf(w.x, v.x, aa); aa = fmaf(w.y, v.y, aa);
                    aa = fmaf(w.z, v.z, aa); aa = fmaf(w.w, v.w, aa);
                }
                float p = fmaxf(aa, 0.0f) * w2s;
                p += __shfl_xor(p, 1);  p += __shfl_xor(p, 2);
                p += __shfl_xor(p, 4);  p += __shfl_xor(p, 8);
                p += __shfl_xor(p, 16);
                float hz = sigm_f(p + b2s);
                float sv = __expf(cum_r);
                cum_r += __logf(1.0f - hz + 1e-7f);
                if (s5 == 0) {
                    int row = blk * 16 + rh;
                    out_haz [row * NHZ + jp] = hz;
                    out_surv[row * NHZ + jp] = sv;
                    if (jp == NHZ - 1) out_pg[row] = 1.0f - sv;
                }
            }
            __syncthreads();
        }

        float* t0 = zA; zA = zB; zB = t0;
        t0 = fP; fP = fN; fN = t0;
    }
}

// ---------------- launch ----------------

extern "C" void kernel_launch(void* const* d_in, const int* in_sizes, int n_in,
                              void* d_out, int out_size, void* d_ws, size_t ws_size,
                              hipStream_t stream) {
    const float* X        = (const float*)d_in[0];
    const float* Mask     = (const float*)d_in[1];
    const float* gru_w_ih = (const float*)d_in[2];
    const float* gru_w_hh = (const float*)d_in[3];
    const float* gru_b_ih = (const float*)d_in[4];
    const float* gru_b_hh = (const float*)d_in[5];
    const float* z0_w     = (const float*)d_in[6];
    const float* z0_b     = (const float*)d_in[7];
    const float* tproj_w  = (const float*)d_in[8];
    const float* tproj_b  = (const float*)d_in[9];
    const float* ode_w1   = (const float*)d_in[10];
    const float* ode_b1   = (const float*)d_in[11];
    const float* ode_w2   = (const float*)d_in[12];
    const float* ode_b2   = (const float*)d_in[13];
    const float* ode_w3   = (const float*)d_in[14];
    const float* ode_b3   = (const float*)d_in[15];
    const float* sh_w1    = (const float*)d_in[16];
    const float* sh_b1    = (const float*)d_in[17];
    const float* sh_w2    = (const float*)d_in[18];
    const float* sh_b2    = (const float*)d_in[19];

    float* ws    = (float*)d_ws;
    float* w1p   = ws;                    // 34816
    float* w2p   = w1p + 34816;           // 65536
    float* w3p   = w2p + 65536;           // 32768
    float* tembs = w3p + 32768;           // 136 -> end 133256 floats (16B-aligned)
    unsigned short* Brz = (unsigned short*)(ws + 133256);   // 163840
    unsigned short* Bnu = Brz + 163840;                     // 16384
    unsigned short* Bnh = Bnu + 16384;                      // 65536
    unsigned short* Bz0 = Bnh + 65536;                      // 65536  (total ~1.16MB)

    float* out      = (float*)d_out;
    float* out_haz  = out;                              // 4096*48
    float* out_surv = out + 196608;                     // 4096*48
    float* out_mean = out + 393216;                     // 4096*128
    float* out_lv   = out + 917504;                     // 4096*128
    float* out_pg   = out + 1441792;                    // 4096

    pack4_k<<<(256*136 + 255) / 256, 256, 0, stream>>>(ode_w1, w1p, 256, 136);
    pack4_k<<<(256*256 + 255) / 256, 256, 0, stream>>>(ode_w2, w2p, 256, 256);
    pack4_k<<<(128*256 + 255) / 256, 256, 0, stream>>>(ode_w3, w3p, 128, 256);
    temb_k<<<1, 64, 0, stream>>>(tproj_w, tproj_b, tembs);

    packBrz_k<<<(32*10*512) / 256, 256, 0, stream>>>(gru_w_ih, gru_w_hh, Brz);
    packB_k<<<(16*2*512) / 256, 256, 0, stream>>>(gru_w_ih + 512 * 64,  Bnu, 64,  16, 2);
    packB_k<<<(16*8*512) / 256, 256, 0, stream>>>(gru_w_hh + 512 * 256, Bnh, 256, 16, 8);
    packB_k<<<(16*8*512) / 256, 256, 0, stream>>>(z0_w,                 Bz0, 256, 16, 8);

    gru_mfma_k<<<BB / 16, 512, 0, stream>>>(X, Mask, Brz, Bnu, Bnh, Bz0,
                                            gru_b_ih, gru_b_hh, z0_b, out_mean, out_lv);

    ode_head_k<<<BB / 16, 512, 0, stream>>>(out_mean, w1p, w2p, w3p,
                                            ode_b1, ode_b2, ode_b3, tembs,
                                            sh_w1, sh_b1, sh_w2, sh_b2,
                                            out_haz, out_surv, out_pg);
}

// Round 11
// 691.963 us; speedup vs baseline: 20.8374x; 2.0732x over previous
//
#include <hip/hip_runtime.h>
#include <math.h>

#define BB 4096
#define TT 48
#define DD 32
#define HH 256
#define LL 128
#define HID 256
#define EE 8
#define NHZ 48
#define NS 8              // RK4 macro steps (dense-output Hermite between knots)
#define NTEMB (2*NS+1)    // 17 precomputed time-embeddings

typedef __attribute__((ext_vector_type(8))) short bf16x8;   // 8 bf16 = 4 VGPRs
typedef __attribute__((ext_vector_type(4))) float f32x4;

#define MFMA_BF16(a,b,c) __builtin_amdgcn_mfma_f32_16x16x32_bf16((a),(b),(c),0,0,0)

__device__ __forceinline__ float sigm_f(float x) {
    return 1.0f / (1.0f + __expf(-x));
}
__device__ __forceinline__ float tanh_f(float x) {
    x = fminf(fmaxf(x, -15.0f), 15.0f);
    float e = __expf(2.0f * x);
    return (e - 1.0f) / (e + 1.0f);
}
__device__ __forceinline__ float4 axpy4(float s, float4 a, float4 z) {
    return make_float4(fmaf(s, a.x, z.x), fmaf(s, a.y, z.y),
                       fmaf(s, a.z, z.z), fmaf(s, a.w, z.w));
}
__device__ __forceinline__ unsigned short f2bf(float x) {   // RNE fp32->bf16
    union { float f; unsigned u; } a; a.f = x;
    unsigned r = a.u + 0x7FFFu + ((a.u >> 16) & 1u);
    return (unsigned short)(r >> 16);
}

// ---------------- prep kernels ----------------

__global__ void temb_k(const float* __restrict__ tproj_w, const float* __restrict__ tproj_b,
                       float* __restrict__ tembs) {
    int i = blockIdx.x * 64 + threadIdx.x;
    if (i >= NTEMB) return;
    float t = (float)i / (float)(2 * NS);
    const float PI = 3.14159265358979323846f;
    float emb[8];
    #pragma unroll
    for (int m = 0; m < 4; ++m) {
        float pos = t * (float)(m + 1) * PI;
        emb[m]     = sinf(pos);
        emb[4 + m] = cosf(pos);
    }
    #pragma unroll
    for (int o = 0; o < 8; ++o) {
        float a = tproj_b[o];
        #pragma unroll
        for (int k = 0; k < 8; ++k) a = fmaf(tproj_w[o * 8 + k], emb[k], a);
        tembs[i * 8 + o] = a;
    }
}

// tembW1[ti][n] = b1[n] + sum_k W1[n][128+k] * temb(ti)[k]
__global__ void tembW1_k(const float* __restrict__ w1, const float* __restrict__ b1,
                         const float* __restrict__ tembs, float* __restrict__ out) {
    int i = blockIdx.x * 256 + threadIdx.x;
    if (i >= NTEMB * 256) return;
    int ti = i >> 8, n = i & 255;
    float a = b1[n];
    #pragma unroll
    for (int k = 0; k < 8; ++k) a = fmaf(w1[n * 136 + 128 + k], tembs[ti * 8 + k], a);
    out[i] = a;
}

// B-fragment packers (bf16). Fragment = 512 bf16: element (lane*8+j) holds
// B[k][n] with k = ks*32 + (lane>>4)*8 + j, n = nt*16 + (lane&15).

__global__ void packBrz_k(const float* __restrict__ w_ih, const float* __restrict__ w_hh,
                          unsigned short* __restrict__ dst) {
    int i = blockIdx.x * 256 + threadIdx.x;      // 32 nt * 10 ks * 512
    if (i >= 32 * 10 * 512) return;
    int frag = i >> 9, e = i & 511;
    int lane = e >> 3, j = e & 7;
    int nt = frag / 10, ks = frag % 10;
    int k = ks * 32 + ((lane >> 4) << 3) + j;
    int n = nt * 16 + (lane & 15);
    float v = (k < 64) ? w_ih[n * 64 + k] : w_hh[n * 256 + (k - 64)];
    dst[i] = f2bf(v);
}

__global__ void packB_k(const float* __restrict__ src, unsigned short* __restrict__ dst,
                        int K, int NT, int NKS) {
    int i = blockIdx.x * 256 + threadIdx.x;
    if (i >= NT * NKS * 512) return;
    int frag = i >> 9, e = i & 511;
    int lane = e >> 3, j = e & 7;
    int nt = frag / NKS, ks = frag % NKS;
    int k = ks * 32 + ((lane >> 4) << 3) + j;
    int n = nt * 16 + (lane & 15);
    dst[i] = f2bf(src[n * K + k]);
}

// ---------------- GRU encoder via MFMA (round-10 verbatim, validated) ----------------

__global__ __launch_bounds__(512, 2) void gru_mfma_k(
    const float* __restrict__ Xp, const float* __restrict__ Mp,
    const unsigned short* __restrict__ Brz,   // [32 nt][10 ks][512]
    const unsigned short* __restrict__ Bnu,   // [16 nt][ 2 ks][512]
    const unsigned short* __restrict__ Bnh,   // [16 nt][ 8 ks][512]
    const unsigned short* __restrict__ Bz0,   // [16 nt][ 8 ks][512]
    const float* __restrict__ b_ih, const float* __restrict__ b_hh,
    const float* __restrict__ z0_b,
    float* __restrict__ out_mean, float* __restrict__ out_lv) {

    __shared__ unsigned short h_bf[16 * 256];  // 8KB, swizzled
    __shared__ unsigned short u_bf[16 * 64];   // 2KB, swizzled
    __shared__ float obs[16];

    int tid = threadIdx.x, blk = blockIdx.x;
    int lane = tid & 63, w = tid >> 6;
    int l4 = lane >> 4, l15 = lane & 15;

    for (int e = tid; e < 16 * 256; e += 512) h_bf[e] = 0;

    float brz0[2], brz1[2], bin_[2], bhn_[2];
    int hcol[2];
    #pragma unroll
    for (int gg = 0; gg < 2; ++gg) {
        int n = (2 * w + gg) * 16 + l15;
        hcol[gg] = n;
        brz0[gg] = b_ih[n]       + b_hh[n];
        brz1[gg] = b_ih[256 + n] + b_hh[256 + n];
        bin_[gg] = b_ih[512 + n];
        bhn_[gg] = b_hh[512 + n];
    }
    float h_st[2][4] = {{0,0,0,0},{0,0,0,0}};

    __syncthreads();

    int arow = l15, asw = (arow & 7) << 4;

    for (int t = TT - 1; t >= 0; --t) {
        if (tid < 256) {
            int r = tid >> 4, c4 = tid & 15;
            const float* base = (c4 < 8 ? Xp : Mp) + (size_t)(blk * 16 + r) * (TT * DD) + t * DD;
            float4 v = ((const float4*)base)[c4 & 7];
            ushort4 p;
            p.x = f2bf(v.x); p.y = f2bf(v.y); p.z = f2bf(v.z); p.w = f2bf(v.w);
            int k0 = (c4 < 8) ? c4 * 4 : 32 + (c4 - 8) * 4;
            int off = r * 128 + ((k0 * 2) ^ ((r & 7) << 4));
            *(ushort4*)((char*)u_bf + off) = p;
        }
        if (tid < 16) {
            const float4* mrow = (const float4*)(Mp + (size_t)(blk * 16 + tid) * (TT * DD) + t * DD);
            float s = 0.0f;
            #pragma unroll
            for (int i = 0; i < 8; ++i) { float4 v = mrow[i]; s += v.x + v.y + v.z + v.w; }
            obs[tid] = (s > 0.0f) ? 1.0f : 0.0f;
        }
        bf16x8 ah[8];
        #pragma unroll
        for (int ks = 0; ks < 8; ++ks)
            ah[ks] = *(const bf16x8*)((const char*)h_bf + (arow * 512 + ((ks * 64 + l4 * 16) ^ asw)));
        __syncthreads();

        bf16x8 au[2];
        #pragma unroll
        for (int ks = 0; ks < 2; ++ks)
            au[ks] = *(const bf16x8*)((const char*)u_bf + (arow * 128 + ((ks * 64 + l4 * 16) ^ asw)));

        #pragma unroll
        for (int gg = 0; gg < 2; ++gg) {
            int g = 2 * w + gg;
            f32x4 accr = {0,0,0,0}, accz = {0,0,0,0}, acci = {0,0,0,0}, acch = {0,0,0,0};
            #pragma unroll
            for (int ks = 0; ks < 10; ++ks) {
                bf16x8 a = (ks < 2) ? au[ks] : ah[ks - 2];
                bf16x8 br = *(const bf16x8*)(Brz + ((g * 10 + ks) * 512 + lane * 8));
                bf16x8 bz = *(const bf16x8*)(Brz + (((16 + g) * 10 + ks) * 512 + lane * 8));
                accr = MFMA_BF16(a, br, accr);
                accz = MFMA_BF16(a, bz, accz);
            }
            #pragma unroll
            for (int ks = 0; ks < 2; ++ks) {
                bf16x8 b = *(const bf16x8*)(Bnu + ((g * 2 + ks) * 512 + lane * 8));
                acci = MFMA_BF16(au[ks], b, acci);
            }
            #pragma unroll
            for (int ks = 0; ks < 8; ++ks) {
                bf16x8 b = *(const bf16x8*)(Bnh + ((g * 8 + ks) * 512 + lane * 8));
                acch = MFMA_BF16(ah[ks], b, acch);
            }
            #pragma unroll
            for (int q = 0; q < 4; ++q) {
                int m = l4 * 4 + q;
                float rg = sigm_f(accr[q] + brz0[gg]);
                float zg = sigm_f(accz[q] + brz1[gg]);
                float nn = tanh_f(acci[q] + bin_[gg] + rg * (acch[q] + bhn_[gg]));
                float hnew = (1.0f - zg) * nn + zg * h_st[gg][q];
                float o = obs[m];
                float hs = o * hnew + (1.0f - o) * h_st[gg][q];
                h_st[gg][q] = hs;
                int off = m * 512 + ((hcol[gg] * 2) ^ ((m & 7) << 4));
                *(unsigned short*)((char*)h_bf + off) = f2bf(hs);
            }
        }
        __syncthreads();
    }

    bf16x8 ahf[8];
    #pragma unroll
    for (int ks = 0; ks < 8; ++ks)
        ahf[ks] = *(const bf16x8*)((const char*)h_bf + (arow * 512 + ((ks * 64 + l4 * 16) ^ asw)));
    #pragma unroll
    for (int gg = 0; gg < 2; ++gg) {
        int nt = 2 * w + gg;
        f32x4 acc = {0,0,0,0};
        #pragma unroll
        for (int ks = 0; ks < 8; ++ks) {
            bf16x8 b = *(const bf16x8*)(Bz0 + ((nt * 8 + ks) * 512 + lane * 8));
            acc = MFMA_BF16(ahf[ks], b, acc);
        }
        int n = nt * 16 + l15;
        float bb = z0_b[n];
        #pragma unroll
        for (int q = 0; q < 4; ++q) {
            int m = l4 * 4 + q;
            int row = blk * 16 + m;
            float v = acc[q] + bb;
            if (n < 128) out_mean[row * LL + n] = v;
            else         out_lv  [row * LL + (n - 128)] = v;
        }
    }
}

// ---------------- ODE dynamics eval via MFMA ----------------
// az: bf16 A-layout of current state [16 rows][128 k] (XOR-swizzled).
// Wave w owns n-tiles 2w,2w+1 (phases A,B) and tile w (phase C, N=128).
// C/D layout: acc[q] -> (m = (lane>>4)*4+q, n = nt*16 + (lane&15)) [validated rnd 10].

__device__ __forceinline__ void ode_f_mfma(
    const unsigned short* __restrict__ az, unsigned short* __restrict__ h1b,
    unsigned short* __restrict__ h2b, float* __restrict__ fo,
    const unsigned short* __restrict__ B1, const unsigned short* __restrict__ B2,
    const unsigned short* __restrict__ B3,
    const float* __restrict__ tW1,   // tembW1 + ti*256 (includes b1)
    float b2n0, float b2n1, float b3n, int lane, int w) {

    int l4 = lane >> 4, l15 = lane & 15;
    int arow = l15, asw = (arow & 7) << 4;

    // phase A: h1 = tanh(W1z·z + tembW1(t))   K=128 -> 4 ks
    bf16x8 a4[4];
    #pragma unroll
    for (int ks = 0; ks < 4; ++ks)
        a4[ks] = *(const bf16x8*)((const char*)az + (arow * 256 + ((ks * 64 + l4 * 16) ^ asw)));
    #pragma unroll
    for (int gg = 0; gg < 2; ++gg) {
        int nt = 2 * w + gg, n = nt * 16 + l15;
        f32x4 acc = {0,0,0,0};
        #pragma unroll
        for (int ks = 0; ks < 4; ++ks) {
            bf16x8 b = *(const bf16x8*)(B1 + ((nt * 4 + ks) * 512 + lane * 8));
            acc = MFMA_BF16(a4[ks], b, acc);
        }
        float tb = tW1[n];
        #pragma unroll
        for (int q = 0; q < 4; ++q) {
            int m = l4 * 4 + q;
            float v = tanh_f(acc[q] + tb);
            *(unsigned short*)((char*)h1b + (m * 512 + ((n * 2) ^ ((m & 7) << 4)))) = f2bf(v);
        }
    }
    __syncthreads();

    // phase B: h2 = tanh(W2·h1 + b2)   K=256 -> 8 ks
    bf16x8 a8[8];
    #pragma unroll
    for (int ks = 0; ks < 8; ++ks)
        a8[ks] = *(const bf16x8*)((const char*)h1b + (arow * 512 + ((ks * 64 + l4 * 16) ^ asw)));
    #pragma unroll
    for (int gg = 0; gg < 2; ++gg) {
        int nt = 2 * w + gg, n = nt * 16 + l15;
        f32x4 acc = {0,0,0,0};
        #pragma unroll
        for (int ks = 0; ks < 8; ++ks) {
            bf16x8 b = *(const bf16x8*)(B2 + ((nt * 8 + ks) * 512 + lane * 8));
            acc = MFMA_BF16(a8[ks], b, acc);
        }
        float bb = (gg == 0) ? b2n0 : b2n1;
        #pragma unroll
        for (int q = 0; q < 4; ++q) {
            int m = l4 * 4 + q;
            float v = tanh_f(acc[q] + bb);
            *(unsigned short*)((char*)h2b + (m * 512 + ((n * 2) ^ ((m & 7) << 4)))) = f2bf(v);
        }
    }
    __syncthreads();

    // phase C: fo = W3·h2 + b3   N=128, wave w -> tile w
    #pragma unroll
    for (int ks = 0; ks < 8; ++ks)
        a8[ks] = *(const bf16x8*)((const char*)h2b + (arow * 512 + ((ks * 64 + l4 * 16) ^ asw)));
    {
        f32x4 acc = {0,0,0,0};
        #pragma unroll
        for (int ks = 0; ks < 8; ++ks) {
            bf16x8 b = *(const bf16x8*)(B3 + ((w * 8 + ks) * 512 + lane * 8));
            acc = MFMA_BF16(a8[ks], b, acc);
        }
        int n = w * 16 + l15;
        #pragma unroll
        for (int q = 0; q < 4; ++q)
            fo[(l4 * 4 + q) * 128 + n] = acc[q] + b3n;
    }
    __syncthreads();
}

// ---------------- ODE (8-step RK4 + Hermite dense output) + head ----------------
// fp32 state/combines/head; bf16 MFMA evals. 512 thr, grid 256, LDS 76KB.

__global__ __launch_bounds__(512, 2) void ode_head_mfma_k(
    const float* __restrict__ zinit,
    const unsigned short* __restrict__ B1, const unsigned short* __restrict__ B2,
    const unsigned short* __restrict__ B3,
    const float* __restrict__ tembW1, const float* __restrict__ b2, const float* __restrict__ b3,
    const float* __restrict__ shw1g, const float* __restrict__ shb1,
    const float* __restrict__ shw2, const float* __restrict__ shb2,
    float* __restrict__ out_haz, float* __restrict__ out_surv, float* __restrict__ out_pg) {

    __shared__ __align__(16) float bufA [2048];              // 8KB z knot s
    __shared__ __align__(16) float bufB [2048];              // 8KB z knot s+1
    __shared__ __align__(16) float bufFP[2048];              // 8KB f knot s
    __shared__ __align__(16) float bufFN[2048];              // 8KB f scratch
    __shared__ __align__(16) float ztl  [2048];              // 8KB stage/z-theta
    __shared__ __align__(16) unsigned short az [16 * 128];   // 4KB bf16 A of state
    __shared__ __align__(16) unsigned short h1b[16 * 256];   // 8KB
    __shared__ __align__(16) unsigned short h2b[16 * 256];   // 8KB
    __shared__ __align__(16) float w1h[32 * 128];            // 16KB head W1 packed

    int tid = threadIdx.x, blk = blockIdx.x;
    int lane = tid & 63, w = tid >> 6;
    int l15 = lane & 15;
    int s5 = tid & 31, rh = tid >> 5;

    float b2n0 = b2[(2 * w) * 16 + l15];
    float b2n1 = b2[(2 * w + 1) * 16 + l15];
    float b3n  = b3[w * 16 + l15];
    float w2s = shw2[s5], b1s = shb1[s5], b2s = shb2[0];
    float cum_r = 0.0f;
    const float4* w1hq = (const float4*)w1h;

    float* zA = bufA; float* zB = bufB;
    float* fP = bufFP; float* fN = bufFN;

    int crow = tid >> 5, ccol = (tid & 31) * 4;
    int azoff = crow * 256 + ((ccol * 2) ^ ((crow & 7) << 4));

    {
        float4 zv = ((const float4*)(zinit + (size_t)blk * 2048))[tid];
        ((float4*)zA)[tid] = zv;
        ushort4 pb; pb.x = f2bf(zv.x); pb.y = f2bf(zv.y); pb.z = f2bf(zv.z); pb.w = f2bf(zv.w);
        *(ushort4*)((char*)az + azoff) = pb;
    }
    for (int e = tid; e < 32 * 128; e += 512) {
        int u = e >> 7, k = e & 127;
        w1h[((k >> 2) * 32 + u) * 4 + (k & 3)] = shw1g[e];
    }
    __syncthreads();

    // f0 = f(z0, t=0)
    ode_f_mfma(az, h1b, h2b, fP, B1, B2, B3, tembW1, b2n0, b2n1, b3n, lane, w);

    const float Hh = 1.0f / (float)NS;

    for (int st = 0; st < NS; ++st) {
        float4 ka, zr0;
        {   // k1 = fP (FSAL)
            float4 f = ((const float4*)fP)[tid];
            zr0 = ((const float4*)zA)[tid];
            ka = f;
            float4 zv = axpy4(0.5f * Hh, f, zr0);
            ((float4*)ztl)[tid] = zv;
            ushort4 pb; pb.x=f2bf(zv.x); pb.y=f2bf(zv.y); pb.z=f2bf(zv.z); pb.w=f2bf(zv.w);
            *(ushort4*)((char*)az + azoff) = pb;
        }
        __syncthreads();
        ode_f_mfma(az, h1b, h2b, fN, B1, B2, B3, tembW1 + (2*st+1)*256, b2n0, b2n1, b3n, lane, w); // k2
        {
            float4 f = ((const float4*)fN)[tid];
            ka = axpy4(2.0f, f, ka);
            float4 zv = axpy4(0.5f * Hh, f, zr0);
            ((float4*)ztl)[tid] = zv;
            ushort4 pb; pb.x=f2bf(zv.x); pb.y=f2bf(zv.y); pb.z=f2bf(zv.z); pb.w=f2bf(zv.w);
            *(ushort4*)((char*)az + azoff) = pb;
        }
        __syncthreads();
        ode_f_mfma(az, h1b, h2b, fN, B1, B2, B3, tembW1 + (2*st+1)*256, b2n0, b2n1, b3n, lane, w); // k3
        {
            float4 f = ((const float4*)fN)[tid];
            ka = axpy4(2.0f, f, ka);
            float4 zv = axpy4(Hh, f, zr0);
            ((float4*)ztl)[tid] = zv;
            ushort4 pb; pb.x=f2bf(zv.x); pb.y=f2bf(zv.y); pb.z=f2bf(zv.z); pb.w=f2bf(zv.w);
            *(ushort4*)((char*)az + azoff) = pb;
        }
        __syncthreads();
        ode_f_mfma(az, h1b, h2b, fN, B1, B2, B3, tembW1 + (2*st+2)*256, b2n0, b2n1, b3n, lane, w); // k4
        {
            float4 f = ((const float4*)fN)[tid];
            float s6 = Hh / 6.0f;
            float4 kk = make_float4(ka.x + f.x, ka.y + f.y, ka.z + f.z, ka.w + f.w);
            float4 zv = axpy4(s6, kk, zr0);
            ((float4*)zB)[tid] = zv;
            ushort4 pb; pb.x=f2bf(zv.x); pb.y=f2bf(zv.y); pb.z=f2bf(zv.z); pb.w=f2bf(zv.w);
            *(ushort4*)((char*)az + azoff) = pb;
        }
        __syncthreads();
        // f_{s+1} (next step's k1, Hermite right-slope)
        ode_f_mfma(az, h1b, h2b, fN, B1, B2, B3, tembW1 + (2*st+2)*256, b2n0, b2n1, b3n, lane, w);

        // ---- emit head at output points inside [st/NS, (st+1)/NS] via Hermite ----
        int jlo = (47 * st + NS - 1) / NS;
        int jhi = (st == NS - 1) ? 47 : (47 * (st + 1) + NS - 1) / NS - 1;
        for (int jp = jlo; jp <= jhi; ++jp) {
            float th  = ((float)NS * (float)jp - 47.0f * (float)st) * (1.0f / 47.0f);
            float th2 = th * th, th3 = th2 * th;
            float c0 = 2.0f * th3 - 3.0f * th2 + 1.0f;
            float c1 = 3.0f * th2 - 2.0f * th3;
            float c2 = Hh * (th3 - 2.0f * th2 + th);
            float c3 = Hh * (th3 - th2);
            {
                float4 za = ((const float4*)zA)[tid];
                float4 zb = ((const float4*)zB)[tid];
                float4 fa = ((const float4*)fP)[tid];
                float4 fb = ((const float4*)fN)[tid];
                float4 zv;
                zv.x = c0*za.x + c1*zb.x + c2*fa.x + c3*fb.x;
                zv.y = c0*za.y + c1*zb.y + c2*fa.y + c3*fb.y;
                zv.z = c0*za.z + c1*zb.z + c2*fa.z + c3*fb.z;
                zv.w = c0*za.w + c1*zb.w + c2*fa.w + c3*fb.w;
                ((float4*)ztl)[tid] = zv;
            }
            __syncthreads();
            {
                float aa = b1s;
                const float4* zrow = (const float4*)(ztl + rh * LL);
                for (int k4 = 0; k4 < 32; ++k4) {
                    float4 wv = w1hq[k4 * 32 + s5];
                    float4 v = zrow[k4];
                    aa = fmaf(wv.x, v.x, aa); aa = fmaf(wv.y, v.y, aa);
                    aa = fmaf(wv.z, v.z, aa); aa = fmaf(wv.w, v.w, aa);
                }
                float p = fmaxf(aa, 0.0f) * w2s;
                p += __shfl_xor(p, 1);  p += __shfl_xor(p, 2);
                p += __shfl_xor(p, 4);  p += __shfl_xor(p, 8);
                p += __shfl_xor(p, 16);
                float hz = sigm_f(p + b2s);
                float sv = __expf(cum_r);
                cum_r += __logf(1.0f - hz + 1e-7f);
                if (s5 == 0) {
                    int row = blk * 16 + rh;
                    out_haz [row * NHZ + jp] = hz;
                    out_surv[row * NHZ + jp] = sv;
                    if (jp == NHZ - 1) out_pg[row] = 1.0f - sv;
                }
            }
            __syncthreads();
        }

        // roll buffers
        float* t0 = zA; zA = zB; zB = t0;
        t0 = fP; fP = fN; fN = t0;
    }
}

// ---------------- launch ----------------

extern "C" void kernel_launch(void* const* d_in, const int* in_sizes, int n_in,
                              void* d_out, int out_size, void* d_ws, size_t ws_size,
                              hipStream_t stream) {
    const float* X        = (const float*)d_in[0];
    const float* Mask     = (const float*)d_in[1];
    const float* gru_w_ih = (const float*)d_in[2];
    const float* gru_w_hh = (const float*)d_in[3];
    const float* gru_b_ih = (const float*)d_in[4];
    const float* gru_b_hh = (const float*)d_in[5];
    const float* z0_w     = (const float*)d_in[6];
    const float* z0_b     = (const float*)d_in[7];
    const float* tproj_w  = (const float*)d_in[8];
    const float* tproj_b  = (const float*)d_in[9];
    const float* ode_w1   = (const float*)d_in[10];
    const float* ode_b1   = (const float*)d_in[11];
    const float* ode_w2   = (const float*)d_in[12];
    const float* ode_b2   = (const float*)d_in[13];
    const float* ode_w3   = (const float*)d_in[14];
    const float* ode_b3   = (const float*)d_in[15];
    const float* sh_w1    = (const float*)d_in[16];
    const float* sh_b1    = (const float*)d_in[17];
    const float* sh_w2    = (const float*)d_in[18];
    const float* sh_b2    = (const float*)d_in[19];

    float* ws     = (float*)d_ws;
    float* tembs  = ws;                        // 136 floats
    float* tembW1 = ws + 256;                  // 17*256 = 4352 -> end 4608
    unsigned short* Brz = (unsigned short*)(ws + 4608);  // 163840
    unsigned short* Bnu = Brz + 163840;                  // 16384
    unsigned short* Bnh = Bnu + 16384;                   // 65536
    unsigned short* Bz0 = Bnh + 65536;                   // 65536
    unsigned short* B1  = Bz0 + 65536;                   // 16*4*512 = 32768
    unsigned short* B2  = B1  + 32768;                   // 16*8*512 = 65536
    unsigned short* B3  = B2  + 65536;                   //  8*8*512 = 32768

    float* out      = (float*)d_out;
    float* out_haz  = out;                              // 4096*48
    float* out_surv = out + 196608;                     // 4096*48
    float* out_mean = out + 393216;                     // 4096*128
    float* out_lv   = out + 917504;                     // 4096*128
    float* out_pg   = out + 1441792;                    // 4096

    temb_k<<<1, 64, 0, stream>>>(tproj_w, tproj_b, tembs);
    tembW1_k<<<(NTEMB * 256 + 255) / 256, 256, 0, stream>>>(ode_w1, ode_b1, tembs, tembW1);

    packBrz_k<<<(32*10*512) / 256, 256, 0, stream>>>(gru_w_ih, gru_w_hh, Brz);
    packB_k<<<(16*2*512) / 256, 256, 0, stream>>>(gru_w_ih + 512 * 64,  Bnu, 64,  16, 2);
    packB_k<<<(16*8*512) / 256, 256, 0, stream>>>(gru_w_hh + 512 * 256, Bnh, 256, 16, 8);
    packB_k<<<(16*8*512) / 256, 256, 0, stream>>>(z0_w,                 Bz0, 256, 16, 8);
    packB_k<<<(16*4*512) / 256, 256, 0, stream>>>(ode_w1, B1, 136, 16, 4);   // k<128 only
    packB_k<<<(16*8*512) / 256, 256, 0, stream>>>(ode_w2, B2, 256, 16, 8);
    packB_k<<<( 8*8*512) / 256, 256, 0, stream>>>(ode_w3, B3, 256,  8, 8);

    gru_mfma_k<<<BB / 16, 512, 0, stream>>>(X, Mask, Brz, Bnu, Bnh, Bz0,
                                            gru_b_ih, gru_b_hh, z0_b, out_mean, out_lv);

    ode_head_mfma_k<<<BB / 16, 512, 0, stream>>>(out_mean, B1, B2, B3,
                                                 tembW1, ode_b2, ode_b3,
                                                 sh_w1, sh_b1, sh_w2, sh_b2,
                                                 out_haz, out_surv, out_pg);
}

// Round 13
// 440.849 us; speedup vs baseline: 32.7067x; 1.5696x over previous
//
#include <hip/hip_runtime.h>
#include <math.h>

#define BB 4096
#define TT 48
#define DD 32
#define HH 256
#define LL 128
#define HID 256
#define EE 8
#define NHZ 48
#define NS 8              // RK4 macro steps (dense-output Hermite between knots)
#define NTEMB (2*NS+1)    // 17 precomputed time-embeddings

typedef __attribute__((ext_vector_type(8))) short bf16x8;   // 8 bf16 = 4 VGPRs
typedef __attribute__((ext_vector_type(4))) float f32x4;

#define MFMA_BF16(a,b,c) __builtin_amdgcn_mfma_f32_16x16x32_bf16((a),(b),(c),0,0,0)

__device__ __forceinline__ float sigm_f(float x) {
    return 1.0f / (1.0f + __expf(-x));
}
__device__ __forceinline__ float tanh_f(float x) {
    x = fminf(fmaxf(x, -15.0f), 15.0f);
    float e = __expf(2.0f * x);
    return (e - 1.0f) / (e + 1.0f);
}
__device__ __forceinline__ float4 axpy4(float s, float4 a, float4 z) {
    return make_float4(fmaf(s, a.x, z.x), fmaf(s, a.y, z.y),
                       fmaf(s, a.z, z.z), fmaf(s, a.w, z.w));
}
__device__ __forceinline__ unsigned short f2bf(float x) {   // RNE fp32->bf16
    union { float f; unsigned u; } a; a.f = x;
    unsigned r = a.u + 0x7FFFu + ((a.u >> 16) & 1u);
    return (unsigned short)(r >> 16);
}

// ---------------- prep kernels ----------------

__global__ void temb_k(const float* __restrict__ tproj_w, const float* __restrict__ tproj_b,
                       float* __restrict__ tembs) {
    int i = blockIdx.x * 64 + threadIdx.x;
    if (i >= NTEMB) return;
    float t = (float)i / (float)(2 * NS);
    const float PI = 3.14159265358979323846f;
    float emb[8];
    #pragma unroll
    for (int m = 0; m < 4; ++m) {
        float pos = t * (float)(m + 1) * PI;
        emb[m]     = sinf(pos);
        emb[4 + m] = cosf(pos);
    }
    #pragma unroll
    for (int o = 0; o < 8; ++o) {
        float a = tproj_b[o];
        #pragma unroll
        for (int k = 0; k < 8; ++k) a = fmaf(tproj_w[o * 8 + k], emb[k], a);
        tembs[i * 8 + o] = a;
    }
}

// tembW1[ti][n] = b1[n] + sum_k W1[n][128+k] * temb(ti)[k]
__global__ void tembW1_k(const float* __restrict__ w1, const float* __restrict__ b1,
                         const float* __restrict__ tembs, float* __restrict__ out) {
    int i = blockIdx.x * 256 + threadIdx.x;
    if (i >= NTEMB * 256) return;
    int ti = i >> 8, n = i & 255;
    float a = b1[n];
    #pragma unroll
    for (int k = 0; k < 8; ++k) a = fmaf(w1[n * 136 + 128 + k], tembs[ti * 8 + k], a);
    out[i] = a;
}

// B-fragment packers (bf16). Fragment = 512 bf16: element (lane*8+j) holds
// B[k][n] with k = ks*32 + (lane>>4)*8 + j, n = nt*16 + (lane&15).

__global__ void packBrz_k(const float* __restrict__ w_ih, const float* __restrict__ w_hh,
                          unsigned short* __restrict__ dst) {
    int i = blockIdx.x * 256 + threadIdx.x;      // 32 nt * 10 ks * 512
    if (i >= 32 * 10 * 512) return;
    int frag = i >> 9, e = i & 511;
    int lane = e >> 3, j = e & 7;
    int nt = frag / 10, ks = frag % 10;
    int k = ks * 32 + ((lane >> 4) << 3) + j;
    int n = nt * 16 + (lane & 15);
    float v = (k < 64) ? w_ih[n * 64 + k] : w_hh[n * 256 + (k - 64)];
    dst[i] = f2bf(v);
}

__global__ void packB_k(const float* __restrict__ src, unsigned short* __restrict__ dst,
                        int K, int NT, int NKS) {
    int i = blockIdx.x * 256 + threadIdx.x;
    if (i >= NT * NKS * 512) return;
    int frag = i >> 9, e = i & 511;
    int lane = e >> 3, j = e & 7;
    int nt = frag / NKS, ks = frag % NKS;
    int k = ks * 32 + ((lane >> 4) << 3) + j;
    int n = nt * 16 + (lane & 15);
    dst[i] = f2bf(src[n * K + k]);
}

// ---------------- GRU encoder via MFMA (+ fused z0 projection) ----------------
// Round-11 structure. NEW: Bnh (131KB) staged in LDS (48x reuse), X/Mask loads
// non-temporal (keep Brz/Bnu L2-resident), launch_bounds(512,1) for VGPR room.

__global__ __launch_bounds__(512, 1) void gru_mfma_k(
    const float* __restrict__ Xp, const float* __restrict__ Mp,
    const unsigned short* __restrict__ Brz,   // [32 nt][10 ks][512]  (L2-streamed)
    const unsigned short* __restrict__ Bnu,   // [16 nt][ 2 ks][512]  (L2-streamed)
    const unsigned short* __restrict__ Bnh,   // [16 nt][ 8 ks][512]  (-> LDS)
    const unsigned short* __restrict__ Bz0,   // [16 nt][ 8 ks][512]
    const float* __restrict__ b_ih, const float* __restrict__ b_hh,
    const float* __restrict__ z0_b,
    float* __restrict__ out_mean, float* __restrict__ out_lv) {

    __shared__ unsigned short h_bf[16 * 256];     // 8KB, swizzled
    __shared__ unsigned short u_bf[16 * 64];      // 2KB, swizzled
    __shared__ unsigned short bnh_lds[16 * 8 * 512]; // 131KB n-gate hh fragments
    __shared__ float obs[16];

    int tid = threadIdx.x, blk = blockIdx.x;
    int lane = tid & 63, w = tid >> 6;
    int l4 = lane >> 4, l15 = lane & 15;

    for (int e = tid; e < 16 * 256; e += 512) h_bf[e] = 0;
    // stage Bnh -> LDS (8192 float4 = 131KB)
    for (int e = tid; e < 8192; e += 512)
        ((f32x4*)bnh_lds)[e] = ((const f32x4*)Bnh)[e];

    float brz0[2], brz1[2], bin_[2], bhn_[2];
    int hcol[2];
    #pragma unroll
    for (int gg = 0; gg < 2; ++gg) {
        int n = (2 * w + gg) * 16 + l15;
        hcol[gg] = n;
        brz0[gg] = b_ih[n]       + b_hh[n];
        brz1[gg] = b_ih[256 + n] + b_hh[256 + n];
        bin_[gg] = b_ih[512 + n];
        bhn_[gg] = b_hh[512 + n];
    }
    float h_st[2][4] = {{0,0,0,0},{0,0,0,0}};

    __syncthreads();

    int arow = l15, asw = (arow & 7) << 4;

    for (int t = TT - 1; t >= 0; --t) {
        if (tid < 256) {
            int r = tid >> 4, c4 = tid & 15;
            const float* base = (c4 < 8 ? Xp : Mp) + (size_t)(blk * 16 + r) * (TT * DD) + t * DD;
            f32x4 v = __builtin_nontemporal_load(((const f32x4*)base) + (c4 & 7));
            ushort4 p;
            p.x = f2bf(v.x); p.y = f2bf(v.y); p.z = f2bf(v.z); p.w = f2bf(v.w);
            int k0 = (c4 < 8) ? c4 * 4 : 32 + (c4 - 8) * 4;
            int off = r * 128 + ((k0 * 2) ^ ((r & 7) << 4));
            *(ushort4*)((char*)u_bf + off) = p;
        }
        if (tid < 16) {
            const f32x4* mrow = (const f32x4*)(Mp + (size_t)(blk * 16 + tid) * (TT * DD) + t * DD);
            float s = 0.0f;
            #pragma unroll
            for (int i = 0; i < 8; ++i) {
                f32x4 v = __builtin_nontemporal_load(mrow + i);
                s += v.x + v.y + v.z + v.w;
            }
            obs[tid] = (s > 0.0f) ? 1.0f : 0.0f;
        }
        bf16x8 ah[8];
        #pragma unroll
        for (int ks = 0; ks < 8; ++ks)
            ah[ks] = *(const bf16x8*)((const char*)h_bf + (arow * 512 + ((ks * 64 + l4 * 16) ^ asw)));
        __syncthreads();

        bf16x8 au[2];
        #pragma unroll
        for (int ks = 0; ks < 2; ++ks)
            au[ks] = *(const bf16x8*)((const char*)u_bf + (arow * 128 + ((ks * 64 + l4 * 16) ^ asw)));

        #pragma unroll
        for (int gg = 0; gg < 2; ++gg) {
            int g = 2 * w + gg;
            f32x4 accr = {0,0,0,0}, accz = {0,0,0,0}, acci = {0,0,0,0}, acch = {0,0,0,0};
            #pragma unroll
            for (int ks = 0; ks < 10; ++ks) {
                bf16x8 a = (ks < 2) ? au[ks] : ah[ks - 2];
                bf16x8 br = *(const bf16x8*)(Brz + ((g * 10 + ks) * 512 + lane * 8));
                bf16x8 bz = *(const bf16x8*)(Brz + (((16 + g) * 10 + ks) * 512 + lane * 8));
                accr = MFMA_BF16(a, br, accr);
                accz = MFMA_BF16(a, bz, accz);
            }
            #pragma unroll
            for (int ks = 0; ks < 2; ++ks) {
                bf16x8 b = *(const bf16x8*)(Bnu + ((g * 2 + ks) * 512 + lane * 8));
                acci = MFMA_BF16(au[ks], b, acci);
            }
            #pragma unroll
            for (int ks = 0; ks < 8; ++ks) {
                bf16x8 b = *(const bf16x8*)(bnh_lds + ((g * 8 + ks) * 512 + lane * 8));
                acch = MFMA_BF16(ah[ks], b, acch);
            }
            #pragma unroll
            for (int q = 0; q < 4; ++q) {
                int m = l4 * 4 + q;
                float rg = sigm_f(accr[q] + brz0[gg]);
                float zg = sigm_f(accz[q] + brz1[gg]);
                float nn = tanh_f(acci[q] + bin_[gg] + rg * (acch[q] + bhn_[gg]));
                float hnew = (1.0f - zg) * nn + zg * h_st[gg][q];
                float o = obs[m];
                float hs = o * hnew + (1.0f - o) * h_st[gg][q];
                h_st[gg][q] = hs;
                int off = m * 512 + ((hcol[gg] * 2) ^ ((m & 7) << 4));
                *(unsigned short*)((char*)h_bf + off) = f2bf(hs);
            }
        }
        __syncthreads();
    }

    bf16x8 ahf[8];
    #pragma unroll
    for (int ks = 0; ks < 8; ++ks)
        ahf[ks] = *(const bf16x8*)((const char*)h_bf + (arow * 512 + ((ks * 64 + l4 * 16) ^ asw)));
    #pragma unroll
    for (int gg = 0; gg < 2; ++gg) {
        int nt = 2 * w + gg;
        f32x4 acc = {0,0,0,0};
        #pragma unroll
        for (int ks = 0; ks < 8; ++ks) {
            bf16x8 b = *(const bf16x8*)(Bz0 + ((nt * 8 + ks) * 512 + lane * 8));
            acc = MFMA_BF16(ahf[ks], b, acc);
        }
        int n = nt * 16 + l15;
        float bb = z0_b[n];
        #pragma unroll
        for (int q = 0; q < 4; ++q) {
            int m = l4 * 4 + q;
            int row = blk * 16 + m;
            float v = acc[q] + bb;
            if (n < 128) out_mean[row * LL + n] = v;
            else         out_lv  [row * LL + (n - 128)] = v;
        }
    }
}

// ---------------- ODE dynamics eval via MFMA (round-11 verbatim, validated) ----------------

__device__ __forceinline__ void ode_f_mfma(
    const unsigned short* __restrict__ az, unsigned short* __restrict__ h1b,
    unsigned short* __restrict__ h2b, float* __restrict__ fo,
    const unsigned short* __restrict__ B1, const unsigned short* __restrict__ B2,
    const unsigned short* __restrict__ B3,
    const float* __restrict__ tW1,   // tembW1 + ti*256 (includes b1)
    float b2n0, float b2n1, float b3n, int lane, int w) {

    int l4 = lane >> 4, l15 = lane & 15;
    int arow = l15, asw = (arow & 7) << 4;

    // phase A: h1 = tanh(W1z·z + tembW1(t))   K=128 -> 4 ks
    bf16x8 a4[4];
    #pragma unroll
    for (int ks = 0; ks < 4; ++ks)
        a4[ks] = *(const bf16x8*)((const char*)az + (arow * 256 + ((ks * 64 + l4 * 16) ^ asw)));
    #pragma unroll
    for (int gg = 0; gg < 2; ++gg) {
        int nt = 2 * w + gg, n = nt * 16 + l15;
        f32x4 acc = {0,0,0,0};
        #pragma unroll
        for (int ks = 0; ks < 4; ++ks) {
            bf16x8 b = *(const bf16x8*)(B1 + ((nt * 4 + ks) * 512 + lane * 8));
            acc = MFMA_BF16(a4[ks], b, acc);
        }
        float tb = tW1[n];
        #pragma unroll
        for (int q = 0; q < 4; ++q) {
            int m = l4 * 4 + q;
            float v = tanh_f(acc[q] + tb);
            *(unsigned short*)((char*)h1b + (m * 512 + ((n * 2) ^ ((m & 7) << 4)))) = f2bf(v);
        }
    }
    __syncthreads();

    // phase B: h2 = tanh(W2·h1 + b2)   K=256 -> 8 ks
    bf16x8 a8[8];
    #pragma unroll
    for (int ks = 0; ks < 8; ++ks)
        a8[ks] = *(const bf16x8*)((const char*)h1b + (arow * 512 + ((ks * 64 + l4 * 16) ^ asw)));
    #pragma unroll
    for (int gg = 0; gg < 2; ++gg) {
        int nt = 2 * w + gg, n = nt * 16 + l15;
        f32x4 acc = {0,0,0,0};
        #pragma unroll
        for (int ks = 0; ks < 8; ++ks) {
            bf16x8 b = *(const bf16x8*)(B2 + ((nt * 8 + ks) * 512 + lane * 8));
            acc = MFMA_BF16(a8[ks], b, acc);
        }
        float bb = (gg == 0) ? b2n0 : b2n1;
        #pragma unroll
        for (int q = 0; q < 4; ++q) {
            int m = l4 * 4 + q;
            float v = tanh_f(acc[q] + bb);
            *(unsigned short*)((char*)h2b + (m * 512 + ((n * 2) ^ ((m & 7) << 4)))) = f2bf(v);
        }
    }
    __syncthreads();

    // phase C: fo = W3·h2 + b3   N=128, wave w -> tile w
    #pragma unroll
    for (int ks = 0; ks < 8; ++ks)
        a8[ks] = *(const bf16x8*)((const char*)h2b + (arow * 512 + ((ks * 64 + l4 * 16) ^ asw)));
    {
        f32x4 acc = {0,0,0,0};
        #pragma unroll
        for (int ks = 0; ks < 8; ++ks) {
            bf16x8 b = *(const bf16x8*)(B3 + ((w * 8 + ks) * 512 + lane * 8));
            acc = MFMA_BF16(a8[ks], b, acc);
        }
        int n = w * 16 + l15;
        #pragma unroll
        for (int q = 0; q < 4; ++q)
            fo[(l4 * 4 + q) * 128 + n] = acc[q] + b3n;
    }
    __syncthreads();
}

// ---------------- ODE (8-step RK4 + Hermite dense output) + head ----------------

__global__ __launch_bounds__(512, 2) void ode_head_mfma_k(
    const float* __restrict__ zinit,
    const unsigned short* __restrict__ B1, const unsigned short* __restrict__ B2,
    const unsigned short* __restrict__ B3,
    const float* __restrict__ tembW1, const float* __restrict__ b2, const float* __restrict__ b3,
    const float* __restrict__ shw1g, const float* __restrict__ shb1,
    const float* __restrict__ shw2, const float* __restrict__ shb2,
    float* __restrict__ out_haz, float* __restrict__ out_surv, float* __restrict__ out_pg) {

    __shared__ __align__(16) float bufA [2048];              // 8KB z knot s
    __shared__ __align__(16) float bufB [2048];              // 8KB z knot s+1
    __shared__ __align__(16) float bufFP[2048];              // 8KB f knot s
    __shared__ __align__(16) float bufFN[2048];              // 8KB f scratch
    __shared__ __align__(16) float ztl  [2048];              // 8KB stage/z-theta
    __shared__ __align__(16) unsigned short az [16 * 128];   // 4KB bf16 A of state
    __shared__ __align__(16) unsigned short h1b[16 * 256];   // 8KB
    __shared__ __align__(16) unsigned short h2b[16 * 256];   // 8KB
    __shared__ __align__(16) float w1h[32 * 128];            // 16KB head W1 packed

    int tid = threadIdx.x, blk = blockIdx.x;
    int lane = tid & 63, w = tid >> 6;
    int l15 = lane & 15;
    int s5 = tid & 31, rh = tid >> 5;

    float b2n0 = b2[(2 * w) * 16 + l15];
    float b2n1 = b2[(2 * w + 1) * 16 + l15];
    float b3n  = b3[w * 16 + l15];
    float w2s = shw2[s5], b1s = shb1[s5], b2s = shb2[0];
    float cum_r = 0.0f;
    const float4* w1hq = (const float4*)w1h;

    float* zA = bufA; float* zB = bufB;
    float* fP = bufFP; float* fN = bufFN;

    int crow = tid >> 5, ccol = (tid & 31) * 4;
    int azoff = crow * 256 + ((ccol * 2) ^ ((crow & 7) << 4));

    {
        float4 zv = ((const float4*)(zinit + (size_t)blk * 2048))[tid];
        ((float4*)zA)[tid] = zv;
        ushort4 pb; pb.x = f2bf(zv.x); pb.y = f2bf(zv.y); pb.z = f2bf(zv.z); pb.w = f2bf(zv.w);
        *(ushort4*)((char*)az + azoff) = pb;
    }
    for (int e = tid; e < 32 * 128; e += 512) {
        int u = e >> 7, k = e & 127;
        w1h[((k >> 2) * 32 + u) * 4 + (k & 3)] = shw1g[e];
    }
    __syncthreads();

    // f0 = f(z0, t=0)
    ode_f_mfma(az, h1b, h2b, fP, B1, B2, B3, tembW1, b2n0, b2n1, b3n, lane, w);

    const float Hh = 1.0f / (float)NS;

    for (int st = 0; st < NS; ++st) {
        float4 ka, zr0;
        {   // k1 = fP (FSAL)
            float4 f = ((const float4*)fP)[tid];
            zr0 = ((const float4*)zA)[tid];
            ka = f;
            float4 zv = axpy4(0.5f * Hh, f, zr0);
            ((float4*)ztl)[tid] = zv;
            ushort4 pb; pb.x=f2bf(zv.x); pb.y=f2bf(zv.y); pb.z=f2bf(zv.z); pb.w=f2bf(zv.w);
            *(ushort4*)((char*)az + azoff) = pb;
        }
        __syncthreads();
        ode_f_mfma(az, h1b, h2b, fN, B1, B2, B3, tembW1 + (2*st+1)*256, b2n0, b2n1, b3n, lane, w); // k2
        {
            float4 f = ((const float4*)fN)[tid];
            ka = axpy4(2.0f, f, ka);
            float4 zv = axpy4(0.5f * Hh, f, zr0);
            ((float4*)ztl)[tid] = zv;
            ushort4 pb; pb.x=f2bf(zv.x); pb.y=f2bf(zv.y); pb.z=f2bf(zv.z); pb.w=f2bf(zv.w);
            *(ushort4*)((char*)az + azoff) = pb;
        }
        __syncthreads();
        ode_f_mfma(az, h1b, h2b, fN, B1, B2, B3, tembW1 + (2*st+1)*256, b2n0, b2n1, b3n, lane, w); // k3
        {
            float4 f = ((const float4*)fN)[tid];
            ka = axpy4(2.0f, f, ka);
            float4 zv = axpy4(Hh, f, zr0);
            ((float4*)ztl)[tid] = zv;
            ushort4 pb; pb.x=f2bf(zv.x); pb.y=f2bf(zv.y); pb.z=f2bf(zv.z); pb.w=f2bf(zv.w);
            *(ushort4*)((char*)az + azoff) = pb;
        }
        __syncthreads();
        ode_f_mfma(az, h1b, h2b, fN, B1, B2, B3, tembW1 + (2*st+2)*256, b2n0, b2n1, b3n, lane, w); // k4
        {
            float4 f = ((const float4*)fN)[tid];
            float s6 = Hh / 6.0f;
            float4 kk = make_float4(ka.x + f.x, ka.y + f.y, ka.z + f.z, ka.w + f.w);
            float4 zv = axpy4(s6, kk, zr0);
            ((float4*)zB)[tid] = zv;
            ushort4 pb; pb.x=f2bf(zv.x); pb.y=f2bf(zv.y); pb.z=f2bf(zv.z); pb.w=f2bf(zv.w);
            *(ushort4*)((char*)az + azoff) = pb;
        }
        __syncthreads();
        // f_{s+1} (next step's k1, Hermite right-slope)
        ode_f_mfma(az, h1b, h2b, fN, B1, B2, B3, tembW1 + (2*st+2)*256, b2n0, b2n1, b3n, lane, w);

        // ---- emit head at output points inside [st/NS, (st+1)/NS] via Hermite ----
        int jlo = (47 * st + NS - 1) / NS;
        int jhi = (st == NS - 1) ? 47 : (47 * (st + 1) + NS - 1) / NS - 1;
        for (int jp = jlo; jp <= jhi; ++jp) {
            float th  = ((float)NS * (float)jp - 47.0f * (float)st) * (1.0f / 47.0f);
            float th2 = th * th, th3 = th2 * th;
            float c0 = 2.0f * th3 - 3.0f * th2 + 1.0f;
            float c1 = 3.0f * th2 - 2.0f * th3;
            float c2 = Hh * (th3 - 2.0f * th2 + th);
            float c3 = Hh * (th3 - th2);
            {
                float4 za = ((const float4*)zA)[tid];
                float4 zb = ((const float4*)zB)[tid];
                float4 fa = ((const float4*)fP)[tid];
                float4 fb = ((const float4*)fN)[tid];
                float4 zv;
                zv.x = c0*za.x + c1*zb.x + c2*fa.x + c3*fb.x;
                zv.y = c0*za.y + c1*zb.y + c2*fa.y + c3*fb.y;
                zv.z = c0*za.z + c1*zb.z + c2*fa.z + c3*fb.z;
                zv.w = c0*za.w + c1*zb.w + c2*fa.w + c3*fb.w;
                ((float4*)ztl)[tid] = zv;
            }
            __syncthreads();
            {
                float aa = b1s;
                const float4* zrow = (const float4*)(ztl + rh * LL);
                for (int k4 = 0; k4 < 32; ++k4) {
                    float4 wv = w1hq[k4 * 32 + s5];
                    float4 v = zrow[k4];
                    aa = fmaf(wv.x, v.x, aa); aa = fmaf(wv.y, v.y, aa);
                    aa = fmaf(wv.z, v.z, aa); aa = fmaf(wv.w, v.w, aa);
                }
                float p = fmaxf(aa, 0.0f) * w2s;
                p += __shfl_xor(p, 1);  p += __shfl_xor(p, 2);
                p += __shfl_xor(p, 4);  p += __shfl_xor(p, 8);
                p += __shfl_xor(p, 16);
                float hz = sigm_f(p + b2s);
                float sv = __expf(cum_r);
                cum_r += __logf(1.0f - hz + 1e-7f);
                if (s5 == 0) {
                    int row = blk * 16 + rh;
                    out_haz [row * NHZ + jp] = hz;
                    out_surv[row * NHZ + jp] = sv;
                    if (jp == NHZ - 1) out_pg[row] = 1.0f - sv;
                }
            }
            __syncthreads();
        }

        // roll buffers
        float* t0 = zA; zA = zB; zB = t0;
        t0 = fP; fP = fN; fN = t0;
    }
}

// ---------------- launch ----------------

extern "C" void kernel_launch(void* const* d_in, const int* in_sizes, int n_in,
                              void* d_out, int out_size, void* d_ws, size_t ws_size,
                              hipStream_t stream) {
    const float* X        = (const float*)d_in[0];
    const float* Mask     = (const float*)d_in[1];
    const float* gru_w_ih = (const float*)d_in[2];
    const float* gru_w_hh = (const float*)d_in[3];
    const float* gru_b_ih = (const float*)d_in[4];
    const float* gru_b_hh = (const float*)d_in[5];
    const float* z0_w     = (const float*)d_in[6];
    const float* z0_b     = (const float*)d_in[7];
    const float* tproj_w  = (const float*)d_in[8];
    const float* tproj_b  = (const float*)d_in[9];
    const float* ode_w1   = (const float*)d_in[10];
    const float* ode_b1   = (const float*)d_in[11];
    const float* ode_w2   = (const float*)d_in[12];
    const float* ode_b2   = (const float*)d_in[13];
    const float* ode_w3   = (const float*)d_in[14];
    const float* ode_b3   = (const float*)d_in[15];
    const float* sh_w1    = (const float*)d_in[16];
    const float* sh_b1    = (const float*)d_in[17];
    const float* sh_w2    = (const float*)d_in[18];
    const float* sh_b2    = (const float*)d_in[19];

    float* ws     = (float*)d_ws;
    float* tembs  = ws;                        // 136 floats
    float* tembW1 = ws + 256;                  // 17*256 = 4352 -> end 4608
    unsigned short* Brz = (unsigned short*)(ws + 4608);  // 163840
    unsigned short* Bnu = Brz + 163840;                  // 16384
    unsigned short* Bnh = Bnu + 16384;                   // 65536
    unsigned short* Bz0 = Bnh + 65536;                   // 65536
    unsigned short* B1  = Bz0 + 65536;                   // 16*4*512 = 32768
    unsigned short* B2  = B1  + 32768;                   // 16*8*512 = 65536
    unsigned short* B3  = B2  + 65536;                   //  8*8*512 = 32768

    float* out      = (float*)d_out;
    float* out_haz  = out;                              // 4096*48
    float* out_surv = out + 196608;                     // 4096*48
    float* out_mean = out + 393216;                     // 4096*128
    float* out_lv   = out + 917504;                     // 4096*128
    float* out_pg   = out + 1441792;                    // 4096

    temb_k<<<1, 64, 0, stream>>>(tproj_w, tproj_b, tembs);
    tembW1_k<<<(NTEMB * 256 + 255) / 256, 256, 0, stream>>>(ode_w1, ode_b1, tembs, tembW1);

    packBrz_k<<<(32*10*512) / 256, 256, 0, stream>>>(gru_w_ih, gru_w_hh, Brz);
    packB_k<<<(16*2*512) / 256, 256, 0, stream>>>(gru_w_ih + 512 * 64,  Bnu, 64,  16, 2);
    packB_k<<<(16*8*512) / 256, 256, 0, stream>>>(gru_w_hh + 512 * 256, Bnh, 256, 16, 8);
    packB_k<<<(16*8*512) / 256, 256, 0, stream>>>(z0_w,                 Bz0, 256, 16, 8);
    packB_k<<<(16*4*512) / 256, 256, 0, stream>>>(ode_w1, B1, 136, 16, 4);   // k<128 only
    packB_k<<<(16*8*512) / 256, 256, 0, stream>>>(ode_w2, B2, 256, 16, 8);
    packB_k<<<( 8*8*512) / 256, 256, 0, stream>>>(ode_w3, B3, 256,  8, 8);

    gru_mfma_k<<<BB / 16, 512, 0, stream>>>(X, Mask, Brz, Bnu, Bnh, Bz0,
                                            gru_b_ih, gru_b_hh, z0_b, out_mean, out_lv);

    ode_head_mfma_k<<<BB / 16, 512, 0, stream>>>(out_mean, B1, B2, B3,
                                                 tembW1, ode_b2, ode_b3,
                                                 sh_w1, sh_b1, sh_w2, sh_b2,
                                                 out_haz, out_surv, out_pg);
}